// Round 1
// baseline (275.269 us; speedup 1.0000x reference)
//
#include <hip/hip_runtime.h>

typedef __attribute__((ext_vector_type(8))) short bf16x8;
typedef __attribute__((ext_vector_type(4))) float f32x4;

constexpr int kB = 2, kN = 4096, kC = 512, kNH = 8, kHD = 64;
constexpr int kBN = kB * kN;                 // 8192
constexpr int kWElems = 262144;              // 512*512
constexpr int kWAll = 6 * kWElems;           // 6 weight matrices
constexpr int kWExtra = 3584;                // dwk(1536) + dwb(512) + dwkT(1536)
constexpr float kQScale = 0.1803368801f;     // (1/8) * log2(e)

__device__ __forceinline__ short f2bf(float f) {
  union { float f; unsigned u; } v; v.f = f;
  unsigned r = v.u + 0x7fffu + ((v.u >> 16) & 1u);
  return (short)(r >> 16);
}
__device__ __forceinline__ float bf2f(short s) {
  union { unsigned u; float f; } v; v.u = ((unsigned)(unsigned short)s) << 16;
  return v.f;
}
__device__ __forceinline__ float exp2_(float x) {
#if __has_builtin(__builtin_amdgcn_exp2f)
  return __builtin_amdgcn_exp2f(x);
#else
  return exp2f(x);
#endif
}
// pack two f32 -> two bf16 (round-half-up) in one dword via v_perm
__device__ __forceinline__ unsigned pk2bf(float a, float b) {
  union { float f; unsigned u; } ua, ub; ua.f = a; ub.f = b;
#if __has_builtin(__builtin_amdgcn_perm)
  return __builtin_amdgcn_perm(ub.u + 0x8000u, ua.u + 0x8000u, 0x07060302u);
#else
  return ((ua.u + 0x8000u) >> 16) | (((ub.u + 0x8000u) >> 16) << 16);
#endif
}

__device__ __forceinline__ bf16x8 ld8(const short* p) { return *(const bf16x8*)p; }
__device__ __forceinline__ bf16x8 ld8(const float* p) {
  float4 a = *(const float4*)p;
  float4 b = *(const float4*)(p + 4);
  bf16x8 r;
  r[0] = f2bf(a.x); r[1] = f2bf(a.y); r[2] = f2bf(a.z); r[3] = f2bf(a.w);
  r[4] = f2bf(b.x); r[5] = f2bf(b.y); r[6] = f2bf(b.z); r[7] = f2bf(b.w);
  return r;
}
__device__ __forceinline__ void stf(short* p, float v) { *p = f2bf(v); }
__device__ __forceinline__ void stf(float* p, float v) { *p = v; }

// async 16B global->LDS (LDS dest wave-uniform base + 16*lane).
__device__ __forceinline__ void gload_lds16(const void* g, void* l) {
  __builtin_amdgcn_global_load_lds(
      (const __attribute__((address_space(1))) void*)g,
      (__attribute__((address_space(3))) void*)l, 16, 0, 0);
}

// K0: classify input dtype on-device.
__global__ void detect_dtype(const unsigned* __restrict__ x, int* __restrict__ flag) {
  const int lane = threadIdx.x & 63;
  unsigned w = x[lane];
  int e = (int)((w >> 7) & 0xffu);
  bool bf = (e >= 100 && e <= 140);
  unsigned long long m = __ballot(bf);
  if (lane == 0) *flag = (__popcll(m) >= 32) ? 1 : 0;
}

// K0b: weights AND x -> bf16 in one launch.
// dst layout: [Wq,Wk,Wv,Wc,Wa,Wco | dwk 1536 | dwb 512 | dwkT 3x512]; xb separate.
constexpr int kW8 = kWAll / 8;        // 196608
constexpr int kX8 = kBN * kC / 8;     // 524288
__global__ __launch_bounds__(256) void convert_all(
    const void* Wq, const void* Wk, const void* Wv, const void* Wc,
    const void* Wa, const void* Wco, const void* dwk, const void* dwb,
    const void* x, const int* __restrict__ flag, short* __restrict__ dst,
    short* __restrict__ xb) {
  const int gtid = blockIdx.x * 256 + threadIdx.x;
  const bool bf = (*flag != 0);
  if (gtid < kW8) {
    const int e = gtid * 8;
    const int t = e >> 18, off = e & (kWElems - 1);
    const void* src = (t == 0) ? Wq : (t == 1) ? Wk : (t == 2) ? Wv
                    : (t == 3) ? Wc : (t == 4) ? Wa : Wco;
    bf16x8 v = bf ? ld8((const short*)src + off) : ld8((const float*)src + off);
    *(bf16x8*)(dst + e) = v;
  } else if (gtid < kW8 + kWExtra) {
    const int eoff = gtid - kW8;
    if (eoff < 1536) {
      dst[kWAll + eoff] = bf ? ((const short*)dwk)[eoff]
                             : f2bf(((const float*)dwk)[eoff]);
    } else if (eoff < 2048) {
      const int i = eoff - 1536;
      dst[kWAll + 1536 + i] = bf ? ((const short*)dwb)[i]
                                 : f2bf(((const float*)dwb)[i]);
    } else {
      const int t2 = eoff - 2048;
      const int tap = t2 >> 9, c = t2 & 511;
      dst[kWAll + 2048 + t2] = bf ? ((const short*)dwk)[c * 3 + tap]
                                  : f2bf(((const float*)dwk)[c * 3 + tap]);
    }
  } else if (gtid < kW8 + kWExtra + kX8) {
    const int e = (gtid - kW8 - kWExtra) * 8;
    bf16x8 v = bf ? ld8((const short*)x + e) : ld8((const float*)x + e);
    *(bf16x8*)(xb + e) = v;
  }
}

// ---------------------------------------------------------------------------
// K1: fused input projection GEMM [8192x512] x [2048x512]^T.
// BK=64 (8 iterations), XOR-source-swizzled staging: LDS[m][ch] holds global
// chunk ch^(m&7) so fragment b128 reads are bank-uniform with no padding.
// ---------------------------------------------------------------------------
__global__ __launch_bounds__(256, 3) void proj_gemm(
    const short* __restrict__ xb, const short* __restrict__ wb,
    short* __restrict__ q, short* __restrict__ k, short* __restrict__ vT,
    short* __restrict__ ci) {
  __shared__ __align__(16) short As[128 * 64];  // 16 KB
  __shared__ __align__(16) short Bs[128 * 64];  // 16 KB
  const int t = threadIdx.x;
  const int wave = t >> 6, lane = t & 63;
  const int row = lane & 15, quad = lane >> 4;
  const int bn = blockIdx.x & 15;
  const int bm = blockIdx.x >> 4;
  const int m0 = bm * 128, n0 = bn * 128;
  const int wm = wave & 1, wn = wave >> 1;
  const int lrow = lane >> 3, lch = lane & 7;   // staging: 8 rows x 8 chunks

  f32x4 acc[4][4];
#pragma unroll
  for (int mi = 0; mi < 4; ++mi)
#pragma unroll
    for (int ni = 0; ni < 4; ++ni)
#pragma unroll
      for (int r = 0; r < 4; ++r) acc[mi][ni][r] = 0.0f;

  for (int k0 = 0; k0 < kC; k0 += 64) {
#pragma unroll
    for (int p = 0; p < 4; ++p) {
      const int m = wave * 32 + p * 8 + lrow;     // tile row this lane stages
      const int kch = lch ^ (m & 7);              // swizzled source chunk
      gload_lds16(xb + (size_t)(m0 + m) * kC + k0 + kch * 8,
                  &As[(wave * 32 + p * 8) * 64]);
      gload_lds16(wb + (size_t)(n0 + m) * kC + k0 + kch * 8,
                  &Bs[(wave * 32 + p * 8) * 64]);
    }
    __syncthreads();

#pragma unroll
    for (int kk2 = 0; kk2 < 2; ++kk2) {
      bf16x8 af[4], bfr[4];
#pragma unroll
      for (int mi = 0; mi < 4; ++mi) {
        const int m = wm * 64 + mi * 16 + row;
        const int ch = (kk2 * 4 + quad) ^ (m & 7);
        af[mi] = *(const bf16x8*)(&As[m * 64 + ch * 8]);
      }
#pragma unroll
      for (int ni = 0; ni < 4; ++ni) {
        const int n = wn * 64 + ni * 16 + row;
        const int ch = (kk2 * 4 + quad) ^ (n & 7);
        bfr[ni] = *(const bf16x8*)(&Bs[n * 64 + ch * 8]);
      }
#pragma unroll
      for (int mi = 0; mi < 4; ++mi)
#pragma unroll
        for (int ni = 0; ni < 4; ++ni)
          acc[mi][ni] = __builtin_amdgcn_mfma_f32_16x16x32_bf16(
              af[mi], bfr[ni], acc[mi][ni], 0, 0, 0);
    }
    __syncthreads();
  }

  const int gc0 = n0 + wn * 64;
  const int mat = gc0 >> 9;
  const float scale = (mat == 0) ? kQScale : 1.0f;
#pragma unroll
  for (int mi = 0; mi < 4; ++mi) {
#pragma unroll
    for (int ni = 0; ni < 4; ++ni) {
#pragma unroll
      for (int r = 0; r < 4; ++r) {
        const int gm = m0 + wm * 64 + mi * 16 + quad * 4 + r;
        const int c_ = ((gc0 + ni * 16) & 511) + row;
        const int b_ = gm >> 12;
        const int n_ = gm & (kN - 1);
        const short bv = f2bf(acc[mi][ni][r] * scale);
        if (mat == 3) {
          ci[(b_ * kN + n_) * kC + c_] = bv;
        } else {
          const int h = c_ >> 6, d = c_ & 63;
          const int bh = b_ * kNH + h;
          if (mat == 0)      q[(bh * kN + n_) * kHD + d] = bv;
          else if (mat == 1) k[(bh * kN + n_) * kHD + d] = bv;
          else               vT[(bh * kHD + d) * kN + n_] = bv;
        }
      }
    }
  }
}

// K2: depthwise conv, vectorized bf16x8 (uses dwkT + dwb from wb).
__global__ __launch_bounds__(256) void dwconv(
    const short* __restrict__ ci, const short* __restrict__ wb,
    short* __restrict__ cb) {
  const int e0 = (blockIdx.x * 256 + threadIdx.x) * 8;
  const int c0 = e0 & (kC - 1);
  const int bn = e0 >> 9;
  const int n_ = bn & (kN - 1);
  bf16x8 xc = ld8(ci + e0);
  bf16x8 xm, xp;
  if (n_ > 0) xm = ld8(ci + e0 - kC);
  else
#pragma unroll
    for (int i = 0; i < 8; ++i) xm[i] = 0;
  if (n_ < kN - 1) xp = ld8(ci + e0 + kC);
  else
#pragma unroll
    for (int i = 0; i < 8; ++i) xp[i] = 0;
  bf16x8 w0 = ld8(wb + kWAll + 2048 + c0);
  bf16x8 w1 = ld8(wb + kWAll + 2048 + 512 + c0);
  bf16x8 w2 = ld8(wb + kWAll + 2048 + 1024 + c0);
  bf16x8 bi = ld8(wb + kWAll + 1536 + c0);
  bf16x8 o;
#pragma unroll
  for (int i = 0; i < 8; ++i) {
    float a = bf2f(bi[i]) + bf2f(xm[i]) * bf2f(w0[i]) +
              bf2f(xc[i]) * bf2f(w1[i]) + bf2f(xp[i]) * bf2f(w2[i]);
    o[i] = f2bf(a);
  }
  *(bf16x8*)(cb + e0) = o;
}

// ---------------------------------------------------------------------------
// K3: flash attention v6.
//  - Occupancy restructure: q-tile per block 128 -> 64 (16 q-rows per wave),
//    grid 512 -> 1024 => 4 blocks/CU (LDS 4x36864=147KB of 160KB), 16 waves/CU
//    vs previous 8. Per-wave serial chain (QK->exp2->pack->PV) now has 4
//    waves/SIMD to hide MFMA/trans/DS latency instead of 2.
//  - K LDS [64][72] double-buffered (bank-uniform b128 reads/writes).
//  - V LDS double-buffered in PERMUTED layout: VbS[d][p], p = c*32+quad*8+j
//    holding V[c*32+(j>>2)*16+quad*4+(j&3)][d] -> PV A-frag is ONE contiguous
//    bank-uniform ds_read_b128.
//  - P^T stays in registers, packed via v_perm round-half-up.
//  - ONE barrier per kt (both tiles double-buffered).
// ---------------------------------------------------------------------------
__global__ __launch_bounds__(256, 4) void attn_flash(
    const short* __restrict__ q, const short* __restrict__ k,
    const short* __restrict__ vT, short* __restrict__ attn) {
  __shared__ __align__(16) short Kb[2][64 * 72];    // 2 x 9216 B
  __shared__ __align__(16) short VbS[2][64 * 72];   // 2 x 9216 B
  const int t = threadIdx.x;
  const int wave = t >> 6;
  const int lane = t & 63;
  const int row = lane & 15;
  const int quad = lane >> 4;

  const int slot = blockIdx.x & 7;
  const int inner = blockIdx.x >> 3;          // 0..127
  const int bh = slot * 2 + (inner & 1);
  const int q0 = (inner >> 1) * 64 + wave * 16;

  const short* qbase = q + (size_t)(bh * kN + q0) * kHD;
  const short* kbase = k + (size_t)bh * kN * kHD;
  const short* vbase = vT + (size_t)bh * kHD * kN;

  bf16x8 qb[2];
  qb[0] = *(const bf16x8*)(qbase + row * kHD + quad * 8);
  qb[1] = *(const bf16x8*)(qbase + row * kHD + 32 + quad * 8);

  f32x4 o[4];   // O^T accumulators (64 d rows x 16 q cols per wave)
#pragma unroll
  for (int jd = 0; jd < 4; ++jd)
#pragma unroll
    for (int r = 0; r < 4; ++r) o[jd][r] = 0.0f;
  float l_ = 0.0f;

  // staging geometry: chunks i0,i1 per thread; sr = row, sc = chunk.
  const int i0 = t, i1 = t + 256;
  const int sr0 = i0 >> 3, sc0 = i0 & 7;
  const int sr1 = i1 >> 3, sc1 = i1 & 7;
  // V permuted write bases: tt = sc&3 -> base1 = (sc>>2)*32 + (tt&1)*16 + (tt&2)*2
  const int vb0 = (sc0 >> 2) * 32 + (sc0 & 1) * 16 + (sc0 & 2) * 2;
  const int vb1 = (sc1 >> 2) * 32 + (sc1 & 1) * 16 + (sc1 & 2) * 2;

  auto stage_v = [&](int buf, bf16x8 v0, bf16x8 v1) {
    *(short4*)(&VbS[buf][sr0 * 72 + vb0]) =
        make_short4(v0[0], v0[1], v0[2], v0[3]);
    *(short4*)(&VbS[buf][sr0 * 72 + vb0 + 8]) =
        make_short4(v0[4], v0[5], v0[6], v0[7]);
    *(short4*)(&VbS[buf][sr1 * 72 + vb1]) =
        make_short4(v1[0], v1[1], v1[2], v1[3]);
    *(short4*)(&VbS[buf][sr1 * 72 + vb1 + 8]) =
        make_short4(v1[4], v1[5], v1[6], v1[7]);
  };

  { // prologue: K0, V0 -> buffer 0
    bf16x8 ka = *(const bf16x8*)(kbase + i0 * 8);
    bf16x8 kb2 = *(const bf16x8*)(kbase + i1 * 8);
    *(bf16x8*)(&Kb[0][sr0 * 72 + sc0 * 8]) = ka;
    *(bf16x8*)(&Kb[0][sr1 * 72 + sc1 * 8]) = kb2;
    bf16x8 v0 = *(const bf16x8*)(vbase + sr0 * kN + sc0 * 8);
    bf16x8 v1 = *(const bf16x8*)(vbase + sr1 * kN + sc1 * 8);
    stage_v(0, v0, v1);
  }
  __syncthreads();

  for (int kt = 0; kt < kN / 64; ++kt) {
    const int cur = kt & 1;
    const bool more = (kt < kN / 64 - 1);
    bf16x8 kn0, kn1, vn0, vn1;
    if (more) {
      kn0 = *(const bf16x8*)(kbase + (kt + 1) * 4096 + i0 * 8);
      kn1 = *(const bf16x8*)(kbase + (kt + 1) * 4096 + i1 * 8);
      vn0 = *(const bf16x8*)(vbase + sr0 * kN + (kt + 1) * 64 + sc0 * 8);
      vn1 = *(const bf16x8*)(vbase + sr1 * kN + (kt + 1) * 64 + sc1 * 8);
    }

    // ---- QK: S^T strips (64 k rows x 16 q cols) ----
    f32x4 s[4];
#pragma unroll
    for (int jk = 0; jk < 4; ++jk)
#pragma unroll
      for (int r = 0; r < 4; ++r) s[jk][r] = 0.0f;
#pragma unroll
    for (int jk = 0; jk < 4; ++jk) {
      const short* kr = &Kb[cur][(jk * 16 + row) * 72 + quad * 8];
      bf16x8 a0 = *(const bf16x8*)kr;
      bf16x8 a1 = *(const bf16x8*)(kr + 32);
      s[jk] = __builtin_amdgcn_mfma_f32_16x16x32_bf16(a0, qb[0], s[jk], 0, 0, 0);
      s[jk] = __builtin_amdgcn_mfma_f32_16x16x32_bf16(a1, qb[1], s[jk], 0, 0, 0);
    }

    // ---- softmax (exp2 domain, unnormalized) + in-register P^T B-frags ----
    float rs = 0.0f;
#pragma unroll
    for (int jk = 0; jk < 4; ++jk)
#pragma unroll
      for (int r = 0; r < 4; ++r) {
        float p = exp2_(s[jk][r]);
        s[jk][r] = p;
        rs += p;
      }
    l_ += rs;
    bf16x8 pb[2];
#pragma unroll
    for (int c = 0; c < 2; ++c) {
      union { unsigned u[4]; bf16x8 v; } pu;
      pu.u[0] = pk2bf(s[2 * c][0], s[2 * c][1]);
      pu.u[1] = pk2bf(s[2 * c][2], s[2 * c][3]);
      pu.u[2] = pk2bf(s[2 * c + 1][0], s[2 * c + 1][1]);
      pu.u[3] = pk2bf(s[2 * c + 1][2], s[2 * c + 1][3]);
      pb[c] = pu.v;
    }

    // ---- PV: A = one b128 from permuted V, B = pb regs ----
#pragma unroll
    for (int jd = 0; jd < 4; ++jd) {
      const short* vb = &VbS[cur][(jd * 16 + row) * 72 + quad * 8];
#pragma unroll
      for (int c = 0; c < 2; ++c) {
        bf16x8 av = *(const bf16x8*)(vb + c * 32);
        o[jd] = __builtin_amdgcn_mfma_f32_16x16x32_bf16(av, pb[c], o[jd], 0, 0, 0);
      }
    }

    // ---- stage next tiles into the other buffer; one barrier ----
    if (more) {
      *(bf16x8*)(&Kb[1 - cur][sr0 * 72 + sc0 * 8]) = kn0;
      *(bf16x8*)(&Kb[1 - cur][sr1 * 72 + sc1 * 8]) = kn1;
      stage_v(1 - cur, vn0, vn1);
    }
    __syncthreads();
  }

  // ---- finalize: O^T -> attn[B][N][C], packed 8B stores ----
  const int b_ = bh >> 3, h = bh & 7;
  float lt = l_;
  lt += __shfl_xor(lt, 16);
  lt += __shfl_xor(lt, 32);
  const float linv = 1.0f / lt;
  const int n_ = q0 + row;
  short* ob = attn + (size_t)(b_ * kN + n_) * kC + h * kHD + quad * 4;
#pragma unroll
  for (int jd = 0; jd < 4; ++jd) {
    short4 st = make_short4(f2bf(o[jd][0] * linv), f2bf(o[jd][1] * linv),
                            f2bf(o[jd][2] * linv), f2bf(o[jd][3] * linv));
    *(short4*)(ob + jd * 16) = st;
  }
}

// ---------------------------------------------------------------------------
// K4: out = [attn|cb] @ [Wa|Wo]^T, GEMM M=8192 N=512 K=1024 (K-concat),
// BK=64, XOR-source-swizzled staging.
// ---------------------------------------------------------------------------
template <typename TO>
__device__ __forceinline__ void out_body(
    const short* __restrict__ attn, const short* __restrict__ cb,
    const short* __restrict__ wb, TO* __restrict__ out) {
  __shared__ __align__(16) short As[128 * 64];  // 16 KB
  __shared__ __align__(16) short Bs[64 * 64];   //  8 KB
  const int t = threadIdx.x;
  const int wave = t >> 6, lane = t & 63;
  const int row = lane & 15, quad = lane >> 4;
  const int bn = blockIdx.x & 7;
  const int bm = blockIdx.x >> 3;
  const int m0 = bm * 128, n0 = bn * 64;
  const int wm = wave & 1, wn = wave >> 1;
  const int lrow = lane >> 3, lch = lane & 7;

  f32x4 acc[4][2];
#pragma unroll
  for (int mi = 0; mi < 4; ++mi)
#pragma unroll
    for (int ni = 0; ni < 2; ++ni)
#pragma unroll
      for (int r = 0; r < 4; ++r) acc[mi][ni][r] = 0.0f;

  const short* Wa = wb + 4 * kWElems;
  const short* Wo = wb + 5 * kWElems;

  for (int k0 = 0; k0 < 1024; k0 += 64) {
    const short* Asrc = (k0 < 512) ? attn : cb;
    const short* Bsrc = (k0 < 512) ? Wa : Wo;
    const int ka = k0 & 511;
#pragma unroll
    for (int p = 0; p < 4; ++p) {
      const int m = wave * 32 + p * 8 + lrow;
      const int kch = lch ^ (m & 7);
      gload_lds16(Asrc + (size_t)(m0 + m) * kC + ka + kch * 8,
                  &As[(wave * 32 + p * 8) * 64]);
    }
#pragma unroll
    for (int p = 0; p < 2; ++p) {
      const int n = wave * 16 + p * 8 + lrow;
      const int kch = lch ^ (n & 7);
      gload_lds16(Bsrc + (size_t)(n0 + n) * kC + ka + kch * 8,
                  &Bs[(wave * 16 + p * 8) * 64]);
    }
    __syncthreads();

#pragma unroll
    for (int kk2 = 0; kk2 < 2; ++kk2) {
      bf16x8 af[4], bfr[2];
#pragma unroll
      for (int mi = 0; mi < 4; ++mi) {
        const int m = wm * 64 + mi * 16 + row;
        const int ch = (kk2 * 4 + quad) ^ (m & 7);
        af[mi] = *(const bf16x8*)(&As[m * 64 + ch * 8]);
      }
#pragma unroll
      for (int ni = 0; ni < 2; ++ni) {
        const int n = wn * 32 + ni * 16 + row;
        const int ch = (kk2 * 4 + quad) ^ (n & 7);
        bfr[ni] = *(const bf16x8*)(&Bs[n * 64 + ch * 8]);
      }
#pragma unroll
      for (int mi = 0; mi < 4; ++mi)
#pragma unroll
        for (int ni = 0; ni < 2; ++ni)
          acc[mi][ni] = __builtin_amdgcn_mfma_f32_16x16x32_bf16(
              af[mi], bfr[ni], acc[mi][ni], 0, 0, 0);
    }
    __syncthreads();
  }

#pragma unroll
  for (int mi = 0; mi < 4; ++mi)
#pragma unroll
    for (int ni = 0; ni < 2; ++ni)
#pragma unroll
      for (int r = 0; r < 4; ++r) {
        const int gm = m0 + wm * 64 + mi * 16 + quad * 4 + r;
        const int gc = n0 + wn * 32 + ni * 16 + row;
        stf(out + (size_t)gm * kC + gc, acc[mi][ni][r]);
      }
}

__global__ __launch_bounds__(256, 4) void out_gemm(
    const short* __restrict__ attn, const short* __restrict__ cb,
    const short* __restrict__ wb, const int* __restrict__ flag, void* out) {
  if (*flag)
    out_body<short>(attn, cb, wb, (short*)out);
  else
    out_body<float>(attn, cb, wb, (float*)out);
}

extern "C" void kernel_launch(void* const* d_in, const int* in_sizes, int n_in,
                              void* d_out, int out_size, void* d_ws, size_t ws_size,
                              hipStream_t stream) {
  const void* x   = d_in[0];
  const void* Wq  = d_in[1];
  const void* Wk  = d_in[2];
  const void* Wv  = d_in[3];
  const void* Wa  = d_in[4];
  const void* Wc  = d_in[5];
  const void* dwk = d_in[6];
  const void* dwb = d_in[7];
  const void* Wco = d_in[8];

  short* ws = (short*)d_ws;
  const size_t E = (size_t)kBN * kC;
  int*   flag = (int*)ws;
  short* wb   = ws + 256;
  short* q    = wb + kWAll + kWExtra;
  short* k    = q + E;
  short* vT   = k + E;
  short* ci   = vT + E;
  short* cb   = ci + E;
  short* attn = ci;   // attn overwrites ci (consumed by dwconv first)
  short* xb   = cb;   // consumed by proj_gemm before dwconv writes cb

  detect_dtype<<<1, 64, 0, stream>>>((const unsigned*)x, flag);
  const int cvt_threads = kW8 + kWExtra + kX8;
  convert_all<<<(cvt_threads + 255) / 256, 256, 0, stream>>>(
      Wq, Wk, Wv, Wc, Wa, Wco, dwk, dwb, x, flag, wb, xb);
  proj_gemm<<<1024, 256, 0, stream>>>(xb, wb, q, k, vT, ci);
  dwconv<<<(kBN * kC) / (256 * 8), 256, 0, stream>>>(ci, wb, cb);
  attn_flash<<<1024, 256, 0, stream>>>(q, k, vT, attn);
  out_gemm<<<512, 256, 0, stream>>>(attn, cb, wb, flag, d_out);
}

// Round 2
// 259.213 us; speedup vs baseline: 1.0619x; 1.0619x over previous
//
#include <hip/hip_runtime.h>

typedef __attribute__((ext_vector_type(8))) short bf16x8;
typedef __attribute__((ext_vector_type(4))) float f32x4;

constexpr int kB = 2, kN = 4096, kC = 512, kNH = 8, kHD = 64;
constexpr int kBN = kB * kN;                 // 8192
constexpr int kWElems = 262144;              // 512*512
constexpr int kWAll = 6 * kWElems;           // 6 weight matrices
constexpr int kWExtra = 3584;                // dwk(1536) + dwb(512) + dwkT(1536)
constexpr float kQScale = 0.1803368801f;     // (1/8) * log2(e)

__device__ __forceinline__ short f2bf(float f) {
  union { float f; unsigned u; } v; v.f = f;
  unsigned r = v.u + 0x7fffu + ((v.u >> 16) & 1u);
  return (short)(r >> 16);
}
__device__ __forceinline__ float bf2f(short s) {
  union { unsigned u; float f; } v; v.u = ((unsigned)(unsigned short)s) << 16;
  return v.f;
}
__device__ __forceinline__ float exp2_(float x) {
#if __has_builtin(__builtin_amdgcn_exp2f)
  return __builtin_amdgcn_exp2f(x);
#else
  return exp2f(x);
#endif
}
// pack two f32 -> two bf16 (round-half-up) in one dword via v_perm
__device__ __forceinline__ unsigned pk2bf(float a, float b) {
  union { float f; unsigned u; } ua, ub; ua.f = a; ub.f = b;
#if __has_builtin(__builtin_amdgcn_perm)
  return __builtin_amdgcn_perm(ub.u + 0x8000u, ua.u + 0x8000u, 0x07060302u);
#else
  return ((ua.u + 0x8000u) >> 16) | (((ub.u + 0x8000u) >> 16) << 16);
#endif
}

__device__ __forceinline__ bf16x8 ld8(const short* p) { return *(const bf16x8*)p; }
__device__ __forceinline__ bf16x8 ld8(const float* p) {
  float4 a = *(const float4*)p;
  float4 b = *(const float4*)(p + 4);
  bf16x8 r;
  r[0] = f2bf(a.x); r[1] = f2bf(a.y); r[2] = f2bf(a.z); r[3] = f2bf(a.w);
  r[4] = f2bf(b.x); r[5] = f2bf(b.y); r[6] = f2bf(b.z); r[7] = f2bf(b.w);
  return r;
}
__device__ __forceinline__ void stf(short* p, float v) { *p = f2bf(v); }
__device__ __forceinline__ void stf(float* p, float v) { *p = v; }

// async 16B global->LDS (LDS dest wave-uniform base + 16*lane).
__device__ __forceinline__ void gload_lds16(const void* g, void* l) {
  __builtin_amdgcn_global_load_lds(
      (const __attribute__((address_space(1))) void*)g,
      (__attribute__((address_space(3))) void*)l, 16, 0, 0);
}

// K0: classify input dtype on-device.
__global__ void detect_dtype(const unsigned* __restrict__ x, int* __restrict__ flag) {
  const int lane = threadIdx.x & 63;
  unsigned w = x[lane];
  int e = (int)((w >> 7) & 0xffu);
  bool bf = (e >= 100 && e <= 140);
  unsigned long long m = __ballot(bf);
  if (lane == 0) *flag = (__popcll(m) >= 32) ? 1 : 0;
}

// K0b: weights AND x -> bf16 in one launch.
// dst layout: [Wq,Wk,Wv,Wc,Wa,Wco | dwk 1536 | dwb 512 | dwkT 3x512]; xb separate.
constexpr int kW8 = kWAll / 8;        // 196608
constexpr int kX8 = kBN * kC / 8;     // 524288
__global__ __launch_bounds__(256) void convert_all(
    const void* Wq, const void* Wk, const void* Wv, const void* Wc,
    const void* Wa, const void* Wco, const void* dwk, const void* dwb,
    const void* x, const int* __restrict__ flag, short* __restrict__ dst,
    short* __restrict__ xb) {
  const int gtid = blockIdx.x * 256 + threadIdx.x;
  const bool bf = (*flag != 0);
  if (gtid < kW8) {
    const int e = gtid * 8;
    const int t = e >> 18, off = e & (kWElems - 1);
    const void* src = (t == 0) ? Wq : (t == 1) ? Wk : (t == 2) ? Wv
                    : (t == 3) ? Wc : (t == 4) ? Wa : Wco;
    bf16x8 v = bf ? ld8((const short*)src + off) : ld8((const float*)src + off);
    *(bf16x8*)(dst + e) = v;
  } else if (gtid < kW8 + kWExtra) {
    const int eoff = gtid - kW8;
    if (eoff < 1536) {
      dst[kWAll + eoff] = bf ? ((const short*)dwk)[eoff]
                             : f2bf(((const float*)dwk)[eoff]);
    } else if (eoff < 2048) {
      const int i = eoff - 1536;
      dst[kWAll + 1536 + i] = bf ? ((const short*)dwb)[i]
                                 : f2bf(((const float*)dwb)[i]);
    } else {
      const int t2 = eoff - 2048;
      const int tap = t2 >> 9, c = t2 & 511;
      dst[kWAll + 2048 + t2] = bf ? ((const short*)dwk)[c * 3 + tap]
                                  : f2bf(((const float*)dwk)[c * 3 + tap]);
    }
  } else if (gtid < kW8 + kWExtra + kX8) {
    const int e = (gtid - kW8 - kWExtra) * 8;
    bf16x8 v = bf ? ld8((const short*)x + e) : ld8((const float*)x + e);
    *(bf16x8*)(xb + e) = v;
  }
}

// ---------------------------------------------------------------------------
// K1: fused input projection GEMM [8192x512] x [2048x512]^T.
// BK=64 (8 iterations), XOR-source-swizzled staging: LDS[m][ch] holds global
// chunk ch^(m&7) so fragment b128 reads are bank-uniform with no padding.
// ---------------------------------------------------------------------------
__global__ __launch_bounds__(256, 3) void proj_gemm(
    const short* __restrict__ xb, const short* __restrict__ wb,
    short* __restrict__ q, short* __restrict__ k, short* __restrict__ vT,
    short* __restrict__ ci) {
  __shared__ __align__(16) short As[128 * 64];  // 16 KB
  __shared__ __align__(16) short Bs[128 * 64];  // 16 KB
  const int t = threadIdx.x;
  const int wave = t >> 6, lane = t & 63;
  const int row = lane & 15, quad = lane >> 4;
  const int bn = blockIdx.x & 15;
  const int bm = blockIdx.x >> 4;
  const int m0 = bm * 128, n0 = bn * 128;
  const int wm = wave & 1, wn = wave >> 1;
  const int lrow = lane >> 3, lch = lane & 7;   // staging: 8 rows x 8 chunks

  f32x4 acc[4][4];
#pragma unroll
  for (int mi = 0; mi < 4; ++mi)
#pragma unroll
    for (int ni = 0; ni < 4; ++ni)
#pragma unroll
      for (int r = 0; r < 4; ++r) acc[mi][ni][r] = 0.0f;

  for (int k0 = 0; k0 < kC; k0 += 64) {
#pragma unroll
    for (int p = 0; p < 4; ++p) {
      const int m = wave * 32 + p * 8 + lrow;     // tile row this lane stages
      const int kch = lch ^ (m & 7);              // swizzled source chunk
      gload_lds16(xb + (size_t)(m0 + m) * kC + k0 + kch * 8,
                  &As[(wave * 32 + p * 8) * 64]);
      gload_lds16(wb + (size_t)(n0 + m) * kC + k0 + kch * 8,
                  &Bs[(wave * 32 + p * 8) * 64]);
    }
    __syncthreads();

#pragma unroll
    for (int kk2 = 0; kk2 < 2; ++kk2) {
      bf16x8 af[4], bfr[4];
#pragma unroll
      for (int mi = 0; mi < 4; ++mi) {
        const int m = wm * 64 + mi * 16 + row;
        const int ch = (kk2 * 4 + quad) ^ (m & 7);
        af[mi] = *(const bf16x8*)(&As[m * 64 + ch * 8]);
      }
#pragma unroll
      for (int ni = 0; ni < 4; ++ni) {
        const int n = wn * 64 + ni * 16 + row;
        const int ch = (kk2 * 4 + quad) ^ (n & 7);
        bfr[ni] = *(const bf16x8*)(&Bs[n * 64 + ch * 8]);
      }
#pragma unroll
      for (int mi = 0; mi < 4; ++mi)
#pragma unroll
        for (int ni = 0; ni < 4; ++ni)
          acc[mi][ni] = __builtin_amdgcn_mfma_f32_16x16x32_bf16(
              af[mi], bfr[ni], acc[mi][ni], 0, 0, 0);
    }
    __syncthreads();
  }

  const int gc0 = n0 + wn * 64;
  const int mat = gc0 >> 9;
  const float scale = (mat == 0) ? kQScale : 1.0f;
#pragma unroll
  for (int mi = 0; mi < 4; ++mi) {
#pragma unroll
    for (int ni = 0; ni < 4; ++ni) {
#pragma unroll
      for (int r = 0; r < 4; ++r) {
        const int gm = m0 + wm * 64 + mi * 16 + quad * 4 + r;
        const int c_ = ((gc0 + ni * 16) & 511) + row;
        const int b_ = gm >> 12;
        const int n_ = gm & (kN - 1);
        const short bv = f2bf(acc[mi][ni][r] * scale);
        if (mat == 3) {
          ci[(b_ * kN + n_) * kC + c_] = bv;
        } else {
          const int h = c_ >> 6, d = c_ & 63;
          const int bh = b_ * kNH + h;
          if (mat == 0)      q[(bh * kN + n_) * kHD + d] = bv;
          else if (mat == 1) k[(bh * kN + n_) * kHD + d] = bv;
          else               vT[(bh * kHD + d) * kN + n_] = bv;
        }
      }
    }
  }
}

// K2: depthwise conv, vectorized bf16x8 (uses dwkT + dwb from wb).
__global__ __launch_bounds__(256) void dwconv(
    const short* __restrict__ ci, const short* __restrict__ wb,
    short* __restrict__ cb) {
  const int e0 = (blockIdx.x * 256 + threadIdx.x) * 8;
  const int c0 = e0 & (kC - 1);
  const int bn = e0 >> 9;
  const int n_ = bn & (kN - 1);
  bf16x8 xc = ld8(ci + e0);
  bf16x8 xm, xp;
  if (n_ > 0) xm = ld8(ci + e0 - kC);
  else
#pragma unroll
    for (int i = 0; i < 8; ++i) xm[i] = 0;
  if (n_ < kN - 1) xp = ld8(ci + e0 + kC);
  else
#pragma unroll
    for (int i = 0; i < 8; ++i) xp[i] = 0;
  bf16x8 w0 = ld8(wb + kWAll + 2048 + c0);
  bf16x8 w1 = ld8(wb + kWAll + 2048 + 512 + c0);
  bf16x8 w2 = ld8(wb + kWAll + 2048 + 1024 + c0);
  bf16x8 bi = ld8(wb + kWAll + 1536 + c0);
  bf16x8 o;
#pragma unroll
  for (int i = 0; i < 8; ++i) {
    float a = bf2f(bi[i]) + bf2f(xm[i]) * bf2f(w0[i]) +
              bf2f(xc[i]) * bf2f(w1[i]) + bf2f(xp[i]) * bf2f(w2[i]);
    o[i] = f2bf(a);
  }
  *(bf16x8*)(cb + e0) = o;
}

// ---------------------------------------------------------------------------
// K3: flash attention v7.
//  - Back to v5 tiling: 4 waves x 32 q-rows, q-tile 128, grid 512, 2 blk/CU.
//  - PAIR-PIPELINED: 2 K-tiles per iteration, quad-buffered LDS, ONE barrier
//    per 2 kt. Tile-b's K-frag reads/MFMAs are independent of tile-a's
//    softmax/PV -> compiler interleaves across the pair (T15-style).
//  - K staged via global_load_lds (linear LDS dest + XOR-swizzled SOURCE,
//    proj_gemm pattern): no ds_write issue, no register round-trip.
//    Frag read chunk = (quad+4h) ^ (row&7); bank-uniform (8 lanes/bank).
//  - V stays manual permuted staging: VbS[d][p], p=c*32+quad*8+j holds
//    V[c*32+(j>>2)*16+quad*4+(j&3)][d] -> PV A-frag is one b128 read.
//  - l accumulated via depth-4 tree (was a 16-deep serial add chain).
//  - s_setprio(1) around MFMA clusters (m191: +4-7% attn).
// ---------------------------------------------------------------------------
__global__ __launch_bounds__(256, 2) void attn_flash(
    const short* __restrict__ q, const short* __restrict__ k,
    const short* __restrict__ vT, short* __restrict__ attn) {
  __shared__ __align__(16) short Kb[2][2][64 * 64];    // 32 KB (linear, swz src)
  __shared__ __align__(16) short VbS[2][2][64 * 72];   // 36 KB (permuted)
  const int t = threadIdx.x;
  const int wave = t >> 6;
  const int lane = t & 63;
  const int row = lane & 15;
  const int quad = lane >> 4;

  const int slot = blockIdx.x & 7;
  const int inner = blockIdx.x >> 3;
  const int bh = slot * 2 + (inner & 1);
  const int q0 = (inner >> 1) * 128 + wave * 32;

  const short* qbase = q + (size_t)(bh * kN + q0) * kHD;
  const short* kbase = k + (size_t)bh * kN * kHD;
  const short* vbase = vT + (size_t)bh * kHD * kN;

  bf16x8 qb[2][2];
#pragma unroll
  for (int g = 0; g < 2; ++g) {
    qb[g][0] = *(const bf16x8*)(qbase + (g * 16 + row) * kHD + quad * 8);
    qb[g][1] = *(const bf16x8*)(qbase + (g * 16 + row) * kHD + 32 + quad * 8);
  }

  f32x4 o[2][4];   // O^T accumulators
#pragma unroll
  for (int g = 0; g < 2; ++g)
#pragma unroll
    for (int j = 0; j < 4; ++j)
#pragma unroll
      for (int r = 0; r < 4; ++r) o[g][j][r] = 0.0f;
  float l_[2] = {0.0f, 0.0f};

  // K staging (gload_lds): row r = j*32 + wave*8 + (lane>>3), src chunk
  // (lane&7)^(lane>>3); dest = linear chunk (j*256 + wave*64 + lane).
  const int ksrow = lane >> 3;              // r & 7
  const int kschunk = (lane & 7) ^ ksrow;   // swizzled source chunk

  // V staging geometry: chunks i0,i1 per thread; sr = row, sc = chunk.
  const int i0 = t, i1 = t + 256;
  const int sr0 = i0 >> 3, sc0 = i0 & 7;
  const int sr1 = i1 >> 3, sc1 = i1 & 7;
  const int vb0 = (sc0 >> 2) * 32 + (sc0 & 1) * 16 + (sc0 & 2) * 2;
  const int vb1 = (sc1 >> 2) * 32 + (sc1 & 1) * 16 + (sc1 & 2) * 2;

  auto stage_v = [&](int ph, int tl, bf16x8 v0, bf16x8 v1) {
    *(short4*)(&VbS[ph][tl][sr0 * 72 + vb0]) =
        make_short4(v0[0], v0[1], v0[2], v0[3]);
    *(short4*)(&VbS[ph][tl][sr0 * 72 + vb0 + 8]) =
        make_short4(v0[4], v0[5], v0[6], v0[7]);
    *(short4*)(&VbS[ph][tl][sr1 * 72 + vb1]) =
        make_short4(v1[0], v1[1], v1[2], v1[3]);
    *(short4*)(&VbS[ph][tl][sr1 * 72 + vb1 + 8]) =
        make_short4(v1[4], v1[5], v1[6], v1[7]);
  };
  auto stage_k = [&](int ph, int kt2) {  // kt2 = key-tile index (64 rows)
#pragma unroll
    for (int tl = 0; tl < 2; ++tl)
#pragma unroll
      for (int j = 0; j < 2; ++j)
        gload_lds16(
            kbase + (size_t)((kt2 + tl) * 64 + j * 32 + wave * 8 + ksrow) * 64 +
                kschunk * 8,
            &Kb[ph][tl][j * 2048 + wave * 512]);
  };

  // fragment-read chunk offsets (constant per lane)
  const int c0s = ((quad) ^ (row & 7)) * 8;
  const int c1s = ((quad + 4) ^ (row & 7)) * 8;

  // per-tile compute: QK -> softmax -> PV
  auto tile_step = [&](const short* kt_base, const short* vt_base) {
    f32x4 s[2][4];
#pragma unroll
    for (int g = 0; g < 2; ++g)
#pragma unroll
      for (int jk = 0; jk < 4; ++jk)
#pragma unroll
        for (int r = 0; r < 4; ++r) s[g][jk][r] = 0.0f;
    __builtin_amdgcn_s_setprio(1);
#pragma unroll
    for (int jk = 0; jk < 4; ++jk) {
      const short* kr = kt_base + (jk * 16 + row) * 64;
      bf16x8 a0 = *(const bf16x8*)(kr + c0s);
      bf16x8 a1 = *(const bf16x8*)(kr + c1s);
#pragma unroll
      for (int g = 0; g < 2; ++g) {
        s[g][jk] = __builtin_amdgcn_mfma_f32_16x16x32_bf16(a0, qb[g][0], s[g][jk], 0, 0, 0);
        s[g][jk] = __builtin_amdgcn_mfma_f32_16x16x32_bf16(a1, qb[g][1], s[g][jk], 0, 0, 0);
      }
    }
    __builtin_amdgcn_s_setprio(0);

    bf16x8 pb[2][2];
#pragma unroll
    for (int g = 0; g < 2; ++g) {
      float tj[4];
#pragma unroll
      for (int jk = 0; jk < 4; ++jk) {
#pragma unroll
        for (int r = 0; r < 4; ++r) s[g][jk][r] = exp2_(s[g][jk][r]);
        tj[jk] = (s[g][jk][0] + s[g][jk][1]) + (s[g][jk][2] + s[g][jk][3]);
      }
      l_[g] += (tj[0] + tj[1]) + (tj[2] + tj[3]);
#pragma unroll
      for (int c = 0; c < 2; ++c) {
        union { unsigned u[4]; bf16x8 v; } pu;
        pu.u[0] = pk2bf(s[g][2 * c][0], s[g][2 * c][1]);
        pu.u[1] = pk2bf(s[g][2 * c][2], s[g][2 * c][3]);
        pu.u[2] = pk2bf(s[g][2 * c + 1][0], s[g][2 * c + 1][1]);
        pu.u[3] = pk2bf(s[g][2 * c + 1][2], s[g][2 * c + 1][3]);
        pb[g][c] = pu.v;
      }
    }

    __builtin_amdgcn_s_setprio(1);
#pragma unroll
    for (int jd = 0; jd < 4; ++jd) {
      const short* vb = vt_base + (jd * 16 + row) * 72 + quad * 8;
#pragma unroll
      for (int c = 0; c < 2; ++c) {
        bf16x8 av = *(const bf16x8*)(vb + c * 32);
#pragma unroll
        for (int g = 0; g < 2; ++g)
          o[g][jd] = __builtin_amdgcn_mfma_f32_16x16x32_bf16(
              av, pb[g][c], o[g][jd], 0, 0, 0);
      }
    }
    __builtin_amdgcn_s_setprio(0);
  };

  { // prologue: pair 0 -> phase 0
    stage_k(0, 0);
    bf16x8 a = *(const bf16x8*)(vbase + sr0 * kN + sc0 * 8);
    bf16x8 b = *(const bf16x8*)(vbase + sr1 * kN + sc1 * 8);
    stage_v(0, 0, a, b);
    a = *(const bf16x8*)(vbase + sr0 * kN + 64 + sc0 * 8);
    b = *(const bf16x8*)(vbase + sr1 * kN + 64 + sc1 * 8);
    stage_v(0, 1, a, b);
  }
  __syncthreads();

  for (int p = 0; p < 32; ++p) {
    const int cur = p & 1;
    const bool more = (p < 31);
    bf16x8 vn00, vn01, vn10, vn11;
    if (more) {
      const int kk = (2 * p + 2) * 64;
      stage_k(1 - cur, 2 * p + 2);
      vn00 = *(const bf16x8*)(vbase + sr0 * kN + kk + sc0 * 8);
      vn01 = *(const bf16x8*)(vbase + sr1 * kN + kk + sc1 * 8);
      vn10 = *(const bf16x8*)(vbase + sr0 * kN + kk + 64 + sc0 * 8);
      vn11 = *(const bf16x8*)(vbase + sr1 * kN + kk + 64 + sc1 * 8);
    }

    tile_step(&Kb[cur][0][0], &VbS[cur][0][0]);

    if (more) {
      stage_v(1 - cur, 0, vn00, vn01);
      stage_v(1 - cur, 1, vn10, vn11);
    }

    tile_step(&Kb[cur][1][0], &VbS[cur][1][0]);
    __syncthreads();
  }

  // ---- finalize: O^T -> attn[B][N][C], packed 8B stores ----
  const int b_ = bh >> 3, h = bh & 7;
#pragma unroll
  for (int g = 0; g < 2; ++g) {
    float lt = l_[g];
    lt += __shfl_xor(lt, 16);
    lt += __shfl_xor(lt, 32);
    const float linv = 1.0f / lt;
    const int n_ = q0 + g * 16 + row;
    short* ob = attn + (size_t)(b_ * kN + n_) * kC + h * kHD + quad * 4;
#pragma unroll
    for (int jd = 0; jd < 4; ++jd) {
      short4 st = make_short4(f2bf(o[g][jd][0] * linv), f2bf(o[g][jd][1] * linv),
                              f2bf(o[g][jd][2] * linv), f2bf(o[g][jd][3] * linv));
      *(short4*)(ob + jd * 16) = st;
    }
  }
}

// ---------------------------------------------------------------------------
// K4: out = [attn|cb] @ [Wa|Wo]^T, GEMM M=8192 N=512 K=1024 (K-concat),
// BK=64, XOR-source-swizzled staging.
// ---------------------------------------------------------------------------
template <typename TO>
__device__ __forceinline__ void out_body(
    const short* __restrict__ attn, const short* __restrict__ cb,
    const short* __restrict__ wb, TO* __restrict__ out) {
  __shared__ __align__(16) short As[128 * 64];  // 16 KB
  __shared__ __align__(16) short Bs[64 * 64];   //  8 KB
  const int t = threadIdx.x;
  const int wave = t >> 6, lane = t & 63;
  const int row = lane & 15, quad = lane >> 4;
  const int bn = blockIdx.x & 7;
  const int bm = blockIdx.x >> 3;
  const int m0 = bm * 128, n0 = bn * 64;
  const int wm = wave & 1, wn = wave >> 1;
  const int lrow = lane >> 3, lch = lane & 7;

  f32x4 acc[4][2];
#pragma unroll
  for (int mi = 0; mi < 4; ++mi)
#pragma unroll
    for (int ni = 0; ni < 2; ++ni)
#pragma unroll
      for (int r = 0; r < 4; ++r) acc[mi][ni][r] = 0.0f;

  const short* Wa = wb + 4 * kWElems;
  const short* Wo = wb + 5 * kWElems;

  for (int k0 = 0; k0 < 1024; k0 += 64) {
    const short* Asrc = (k0 < 512) ? attn : cb;
    const short* Bsrc = (k0 < 512) ? Wa : Wo;
    const int ka = k0 & 511;
#pragma unroll
    for (int p = 0; p < 4; ++p) {
      const int m = wave * 32 + p * 8 + lrow;
      const int kch = lch ^ (m & 7);
      gload_lds16(Asrc + (size_t)(m0 + m) * kC + ka + kch * 8,
                  &As[(wave * 32 + p * 8) * 64]);
    }
#pragma unroll
    for (int p = 0; p < 2; ++p) {
      const int n = wave * 16 + p * 8 + lrow;
      const int kch = lch ^ (n & 7);
      gload_lds16(Bsrc + (size_t)(n0 + n) * kC + ka + kch * 8,
                  &Bs[(wave * 16 + p * 8) * 64]);
    }
    __syncthreads();

#pragma unroll
    for (int kk2 = 0; kk2 < 2; ++kk2) {
      bf16x8 af[4], bfr[2];
#pragma unroll
      for (int mi = 0; mi < 4; ++mi) {
        const int m = wm * 64 + mi * 16 + row;
        const int ch = (kk2 * 4 + quad) ^ (m & 7);
        af[mi] = *(const bf16x8*)(&As[m * 64 + ch * 8]);
      }
#pragma unroll
      for (int ni = 0; ni < 2; ++ni) {
        const int n = wn * 32 + ni * 16 + row;
        const int ch = (kk2 * 4 + quad) ^ (n & 7);
        bfr[ni] = *(const bf16x8*)(&Bs[n * 64 + ch * 8]);
      }
#pragma unroll
      for (int mi = 0; mi < 4; ++mi)
#pragma unroll
        for (int ni = 0; ni < 2; ++ni)
          acc[mi][ni] = __builtin_amdgcn_mfma_f32_16x16x32_bf16(
              af[mi], bfr[ni], acc[mi][ni], 0, 0, 0);
    }
    __syncthreads();
  }

#pragma unroll
  for (int mi = 0; mi < 4; ++mi)
#pragma unroll
    for (int ni = 0; ni < 2; ++ni)
#pragma unroll
      for (int r = 0; r < 4; ++r) {
        const int gm = m0 + wm * 64 + mi * 16 + quad * 4 + r;
        const int gc = n0 + wn * 32 + ni * 16 + row;
        stf(out + (size_t)gm * kC + gc, acc[mi][ni][r]);
      }
}

__global__ __launch_bounds__(256, 4) void out_gemm(
    const short* __restrict__ attn, const short* __restrict__ cb,
    const short* __restrict__ wb, const int* __restrict__ flag, void* out) {
  if (*flag)
    out_body<short>(attn, cb, wb, (short*)out);
  else
    out_body<float>(attn, cb, wb, (float*)out);
}

extern "C" void kernel_launch(void* const* d_in, const int* in_sizes, int n_in,
                              void* d_out, int out_size, void* d_ws, size_t ws_size,
                              hipStream_t stream) {
  const void* x   = d_in[0];
  const void* Wq  = d_in[1];
  const void* Wk  = d_in[2];
  const void* Wv  = d_in[3];
  const void* Wa  = d_in[4];
  const void* Wc  = d_in[5];
  const void* dwk = d_in[6];
  const void* dwb = d_in[7];
  const void* Wco = d_in[8];

  short* ws = (short*)d_ws;
  const size_t E = (size_t)kBN * kC;
  int*   flag = (int*)ws;
  short* wb   = ws + 256;
  short* q    = wb + kWAll + kWExtra;
  short* k    = q + E;
  short* vT   = k + E;
  short* ci   = vT + E;
  short* cb   = ci + E;
  short* attn = ci;   // attn overwrites ci (consumed by dwconv first)
  short* xb   = cb;   // consumed by proj_gemm before dwconv writes cb

  detect_dtype<<<1, 64, 0, stream>>>((const unsigned*)x, flag);
  const int cvt_threads = kW8 + kWExtra + kX8;
  convert_all<<<(cvt_threads + 255) / 256, 256, 0, stream>>>(
      Wq, Wk, Wv, Wc, Wa, Wco, dwk, dwb, x, flag, wb, xb);
  proj_gemm<<<1024, 256, 0, stream>>>(xb, wb, q, k, vT, ci);
  dwconv<<<(kBN * kC) / (256 * 8), 256, 0, stream>>>(ci, wb, cb);
  attn_flash<<<512, 256, 0, stream>>>(q, k, vT, attn);
  out_gemm<<<512, 256, 0, stream>>>(attn, cb, wb, flag, d_out);
}

// Round 4
// 245.788 us; speedup vs baseline: 1.1199x; 1.0546x over previous
//
#include <hip/hip_runtime.h>

typedef __attribute__((ext_vector_type(8))) short bf16x8;
typedef __attribute__((ext_vector_type(4))) float f32x4;

constexpr int kB = 2, kN = 4096, kC = 512, kNH = 8, kHD = 64;
constexpr int kBN = kB * kN;                 // 8192
constexpr int kWElems = 262144;              // 512*512
constexpr int kWAll = 6 * kWElems;           // 6 weight matrices
constexpr int kWExtra = 3584;                // dwk(1536) + dwb(512) + dwkT(1536)
constexpr float kQScale = 0.1803368801f;     // (1/8) * log2(e)

__device__ __forceinline__ short f2bf(float f) {
  union { float f; unsigned u; } v; v.f = f;
  unsigned r = v.u + 0x7fffu + ((v.u >> 16) & 1u);
  return (short)(r >> 16);
}
__device__ __forceinline__ float bf2f(short s) {
  union { unsigned u; float f; } v; v.u = ((unsigned)(unsigned short)s) << 16;
  return v.f;
}
__device__ __forceinline__ float exp2_(float x) {
#if __has_builtin(__builtin_amdgcn_exp2f)
  return __builtin_amdgcn_exp2f(x);
#else
  return exp2f(x);
#endif
}
// pack two f32 -> two bf16 (round-half-up) in one dword via v_perm
__device__ __forceinline__ unsigned pk2bf(float a, float b) {
  union { float f; unsigned u; } ua, ub; ua.f = a; ub.f = b;
#if __has_builtin(__builtin_amdgcn_perm)
  return __builtin_amdgcn_perm(ub.u + 0x8000u, ua.u + 0x8000u, 0x07060302u);
#else
  return ((ua.u + 0x8000u) >> 16) | (((ub.u + 0x8000u) >> 16) << 16);
#endif
}

__device__ __forceinline__ bf16x8 ld8(const short* p) { return *(const bf16x8*)p; }
__device__ __forceinline__ bf16x8 ld8(const float* p) {
  float4 a = *(const float4*)p;
  float4 b = *(const float4*)(p + 4);
  bf16x8 r;
  r[0] = f2bf(a.x); r[1] = f2bf(a.y); r[2] = f2bf(a.z); r[3] = f2bf(a.w);
  r[4] = f2bf(b.x); r[5] = f2bf(b.y); r[6] = f2bf(b.z); r[7] = f2bf(b.w);
  return r;
}
__device__ __forceinline__ void stf(short* p, float v) { *p = f2bf(v); }
__device__ __forceinline__ void stf(float* p, float v) { *p = v; }

// async 16B global->LDS (LDS dest wave-uniform base + 16*lane).
__device__ __forceinline__ void gload_lds16(const void* g, void* l) {
  __builtin_amdgcn_global_load_lds(
      (const __attribute__((address_space(1))) void*)g,
      (__attribute__((address_space(3))) void*)l, 16, 0, 0);
}

// K0: classify input dtype on-device.
__global__ void detect_dtype(const unsigned* __restrict__ x, int* __restrict__ flag) {
  const int lane = threadIdx.x & 63;
  unsigned w = x[lane];
  int e = (int)((w >> 7) & 0xffu);
  bool bf = (e >= 100 && e <= 140);
  unsigned long long m = __ballot(bf);
  if (lane == 0) *flag = (__popcll(m) >= 32) ? 1 : 0;
}

// K0b: weights AND x -> bf16 in one launch.
// dst layout: [Wq,Wk,Wv,Wc,Wa,Wco | dwk 1536 | dwb 512 | dwkT 3x512]; xb separate.
constexpr int kW8 = kWAll / 8;        // 196608
constexpr int kX8 = kBN * kC / 8;     // 524288
__global__ __launch_bounds__(256) void convert_all(
    const void* Wq, const void* Wk, const void* Wv, const void* Wc,
    const void* Wa, const void* Wco, const void* dwk, const void* dwb,
    const void* x, const int* __restrict__ flag, short* __restrict__ dst,
    short* __restrict__ xb) {
  const int gtid = blockIdx.x * 256 + threadIdx.x;
  const bool bf = (*flag != 0);
  if (gtid < kW8) {
    const int e = gtid * 8;
    const int t = e >> 18, off = e & (kWElems - 1);
    const void* src = (t == 0) ? Wq : (t == 1) ? Wk : (t == 2) ? Wv
                    : (t == 3) ? Wc : (t == 4) ? Wa : Wco;
    bf16x8 v = bf ? ld8((const short*)src + off) : ld8((const float*)src + off);
    *(bf16x8*)(dst + e) = v;
  } else if (gtid < kW8 + kWExtra) {
    const int eoff = gtid - kW8;
    if (eoff < 1536) {
      dst[kWAll + eoff] = bf ? ((const short*)dwk)[eoff]
                             : f2bf(((const float*)dwk)[eoff]);
    } else if (eoff < 2048) {
      const int i = eoff - 1536;
      dst[kWAll + 1536 + i] = bf ? ((const short*)dwb)[i]
                                 : f2bf(((const float*)dwb)[i]);
    } else {
      const int t2 = eoff - 2048;
      const int tap = t2 >> 9, c = t2 & 511;
      dst[kWAll + 2048 + t2] = bf ? ((const short*)dwk)[c * 3 + tap]
                                  : f2bf(((const float*)dwk)[c * 3 + tap]);
    }
  } else if (gtid < kW8 + kWExtra + kX8) {
    const int e = (gtid - kW8 - kWExtra) * 8;
    bf16x8 v = bf ? ld8((const short*)x + e) : ld8((const float*)x + e);
    *(bf16x8*)(xb + e) = v;
  }
}

// ---------------------------------------------------------------------------
// K1: fused input projection GEMM [8192x512] x [2048x512]^T.
// BK=64 (8 iterations), XOR-source-swizzled staging: LDS[m][ch] holds global
// chunk ch^(m&7) so fragment b128 reads are bank-uniform with no padding.
// ---------------------------------------------------------------------------
__global__ __launch_bounds__(256, 3) void proj_gemm(
    const short* __restrict__ xb, const short* __restrict__ wb,
    short* __restrict__ q, short* __restrict__ k, short* __restrict__ vT,
    short* __restrict__ ci) {
  __shared__ __align__(16) short As[128 * 64];  // 16 KB
  __shared__ __align__(16) short Bs[128 * 64];  // 16 KB
  const int t = threadIdx.x;
  const int wave = t >> 6, lane = t & 63;
  const int row = lane & 15, quad = lane >> 4;
  const int bn = blockIdx.x & 15;
  const int bm = blockIdx.x >> 4;
  const int m0 = bm * 128, n0 = bn * 128;
  const int wm = wave & 1, wn = wave >> 1;
  const int lrow = lane >> 3, lch = lane & 7;   // staging: 8 rows x 8 chunks

  f32x4 acc[4][4];
#pragma unroll
  for (int mi = 0; mi < 4; ++mi)
#pragma unroll
    for (int ni = 0; ni < 4; ++ni)
#pragma unroll
      for (int r = 0; r < 4; ++r) acc[mi][ni][r] = 0.0f;

  for (int k0 = 0; k0 < kC; k0 += 64) {
#pragma unroll
    for (int p = 0; p < 4; ++p) {
      const int m = wave * 32 + p * 8 + lrow;     // tile row this lane stages
      const int kch = lch ^ (m & 7);              // swizzled source chunk
      gload_lds16(xb + (size_t)(m0 + m) * kC + k0 + kch * 8,
                  &As[(wave * 32 + p * 8) * 64]);
      gload_lds16(wb + (size_t)(n0 + m) * kC + k0 + kch * 8,
                  &Bs[(wave * 32 + p * 8) * 64]);
    }
    __syncthreads();

#pragma unroll
    for (int kk2 = 0; kk2 < 2; ++kk2) {
      bf16x8 af[4], bfr[4];
#pragma unroll
      for (int mi = 0; mi < 4; ++mi) {
        const int m = wm * 64 + mi * 16 + row;
        const int ch = (kk2 * 4 + quad) ^ (m & 7);
        af[mi] = *(const bf16x8*)(&As[m * 64 + ch * 8]);
      }
#pragma unroll
      for (int ni = 0; ni < 4; ++ni) {
        const int n = wn * 64 + ni * 16 + row;
        const int ch = (kk2 * 4 + quad) ^ (n & 7);
        bfr[ni] = *(const bf16x8*)(&Bs[n * 64 + ch * 8]);
      }
#pragma unroll
      for (int mi = 0; mi < 4; ++mi)
#pragma unroll
        for (int ni = 0; ni < 4; ++ni)
          acc[mi][ni] = __builtin_amdgcn_mfma_f32_16x16x32_bf16(
              af[mi], bfr[ni], acc[mi][ni], 0, 0, 0);
    }
    __syncthreads();
  }

  const int gc0 = n0 + wn * 64;
  const int mat = gc0 >> 9;
  const float scale = (mat == 0) ? kQScale : 1.0f;
#pragma unroll
  for (int mi = 0; mi < 4; ++mi) {
#pragma unroll
    for (int ni = 0; ni < 4; ++ni) {
#pragma unroll
      for (int r = 0; r < 4; ++r) {
        const int gm = m0 + wm * 64 + mi * 16 + quad * 4 + r;
        const int c_ = ((gc0 + ni * 16) & 511) + row;
        const int b_ = gm >> 12;
        const int n_ = gm & (kN - 1);
        const short bv = f2bf(acc[mi][ni][r] * scale);
        if (mat == 3) {
          ci[(b_ * kN + n_) * kC + c_] = bv;
        } else {
          const int h = c_ >> 6, d = c_ & 63;
          const int bh = b_ * kNH + h;
          if (mat == 0)      q[(bh * kN + n_) * kHD + d] = bv;
          else if (mat == 1) k[(bh * kN + n_) * kHD + d] = bv;
          else               vT[(bh * kHD + d) * kN + n_] = bv;
        }
      }
    }
  }
}

// K2: depthwise conv, vectorized bf16x8 (uses dwkT + dwb from wb).
__global__ __launch_bounds__(256) void dwconv(
    const short* __restrict__ ci, const short* __restrict__ wb,
    short* __restrict__ cb) {
  const int e0 = (blockIdx.x * 256 + threadIdx.x) * 8;
  const int c0 = e0 & (kC - 1);
  const int bn = e0 >> 9;
  const int n_ = bn & (kN - 1);
  bf16x8 xc = ld8(ci + e0);
  bf16x8 xm, xp;
  if (n_ > 0) xm = ld8(ci + e0 - kC);
  else
#pragma unroll
    for (int i = 0; i < 8; ++i) xm[i] = 0;
  if (n_ < kN - 1) xp = ld8(ci + e0 + kC);
  else
#pragma unroll
    for (int i = 0; i < 8; ++i) xp[i] = 0;
  bf16x8 w0 = ld8(wb + kWAll + 2048 + c0);
  bf16x8 w1 = ld8(wb + kWAll + 2048 + 512 + c0);
  bf16x8 w2 = ld8(wb + kWAll + 2048 + 1024 + c0);
  bf16x8 bi = ld8(wb + kWAll + 1536 + c0);
  bf16x8 o;
#pragma unroll
  for (int i = 0; i < 8; ++i) {
    float a = bf2f(bi[i]) + bf2f(xm[i]) * bf2f(w0[i]) +
              bf2f(xc[i]) * bf2f(w1[i]) + bf2f(xp[i]) * bf2f(w2[i]);
    o[i] = f2bf(a);
  }
  *(bf16x8*)(cb + e0) = o;
}

// ---------------------------------------------------------------------------
// K3: flash attention v8 — in-block key-split for occupancy.
//  - 8 waves (512 thr) = 4 q-groups x 2 key-streams. Block q-tile stays 128
//    rows; stream ks handles keys [ks*2048, ks*2048+2048). Each key tile is
//    staged ONCE per block and consumed by 4 waves (128 q-rows): DS traffic
//    per unit work identical to v7, but waves/SIMD doubles (2 blk/CU x 8
//    waves = 4 waves/SIMD) -> latency hiding for the serial
//    QK->exp2->pack->PV chain (round-2 counters: all pipes <45% at 2/SIMD).
//  - K staged via global_load_lds (linear dest + XOR-swizzled SOURCE);
//    V manual permuted staging (PV A-frag = one bank-uniform b128).
//  - Double-buffered; one barrier per iteration.
//  - ks=1 partial O/l combined into ks=0 via LDS overlay (barrier-protected,
//    no global traffic).
// ---------------------------------------------------------------------------
__global__ __launch_bounds__(512, 4) void attn_flash(
    const short* __restrict__ q, const short* __restrict__ k,
    const short* __restrict__ vT, short* __restrict__ attn) {
  __shared__ __align__(16) short Kb[2][2][64 * 64];    // [buf][ks] 32 KB
  __shared__ __align__(16) short VbS[2][2][64 * 72];   // [buf][ks] 36 KB
  const int t = threadIdx.x;
  const int wave = t >> 6;           // 0..7
  const int lane = t & 63;
  const int row = lane & 15;
  const int quad = lane >> 4;
  const int qg = wave & 3;           // q-group (32 rows each)
  const int ks = wave >> 2;          // key-stream (0: keys 0..2047, 1: 2048..4095)

  const int slot = blockIdx.x & 7;
  const int inner = blockIdx.x >> 3;          // 0..63
  const int bh = slot * 2 + (inner & 1);
  const int q0 = (inner >> 1) * 128 + qg * 32;

  const short* qbase = q + (size_t)(bh * kN + q0) * kHD;
  const short* kbase = k + (size_t)bh * kN * kHD;
  const short* vbase = vT + (size_t)bh * kHD * kN;

  bf16x8 qb[2][2];
#pragma unroll
  for (int g = 0; g < 2; ++g) {
    qb[g][0] = *(const bf16x8*)(qbase + (g * 16 + row) * kHD + quad * 8);
    qb[g][1] = *(const bf16x8*)(qbase + (g * 16 + row) * kHD + 32 + quad * 8);
  }

  f32x4 o[2][4];   // O^T partial accumulators (this wave's key half)
#pragma unroll
  for (int g = 0; g < 2; ++g)
#pragma unroll
    for (int j = 0; j < 4; ++j)
#pragma unroll
      for (int r = 0; r < 4; ++r) o[g][j][r] = 0.0f;
  float l_[2] = {0.0f, 0.0f};

  // K staging (gload_lds): wave w stages rows w*8..w*8+7 of BOTH streams'
  // tiles. lane -> row w*8+(lane>>3); dest chunk lane&7 holds source chunk
  // (lane&7)^(lane>>3) (XOR-source swizzle; read side XORs back).
  const int ksrow = lane >> 3;
  const int kschunk = (lane & 7) ^ ksrow;
  auto stage_k = [&](int buf, int kt) {
#pragma unroll
    for (int s2 = 0; s2 < 2; ++s2)
      gload_lds16(
          kbase + (size_t)(s2 * 2048 + kt * 64 + wave * 8 + ksrow) * 64 +
              kschunk * 8,
          &Kb[buf][s2][wave * 512]);
  };

  // V staging: threads 0-255 stage stream-0 tile, 256-511 stream-1 tile.
  // Within a tile: 512 chunks (64 d-rows x 8 col-chunks), 2 per thread.
  const int sv = t >> 8;
  const int ii = t & 255;
  const int i0 = ii, i1 = ii + 256;
  const int sr0 = i0 >> 3, sc0 = i0 & 7;
  const int sr1 = i1 >> 3, sc1 = i1 & 7;
  const int vb0 = (sc0 >> 2) * 32 + (sc0 & 1) * 16 + (sc0 & 2) * 2;
  const int vb1 = (sc1 >> 2) * 32 + (sc1 & 1) * 16 + (sc1 & 2) * 2;

  auto stage_v = [&](int buf, bf16x8 v0, bf16x8 v1) {
    *(short4*)(&VbS[buf][sv][sr0 * 72 + vb0]) =
        make_short4(v0[0], v0[1], v0[2], v0[3]);
    *(short4*)(&VbS[buf][sv][sr0 * 72 + vb0 + 8]) =
        make_short4(v0[4], v0[5], v0[6], v0[7]);
    *(short4*)(&VbS[buf][sv][sr1 * 72 + vb1]) =
        make_short4(v1[0], v1[1], v1[2], v1[3]);
    *(short4*)(&VbS[buf][sv][sr1 * 72 + vb1 + 8]) =
        make_short4(v1[4], v1[5], v1[6], v1[7]);
  };

  // fragment-read chunk offsets (constant per lane)
  const int c0s = ((quad) ^ (row & 7)) * 8;
  const int c1s = ((quad + 4) ^ (row & 7)) * 8;

  // per-tile compute: QK -> softmax -> PV
  auto tile_step = [&](const short* kt_base, const short* vt_base) {
    f32x4 s[2][4];
#pragma unroll
    for (int g = 0; g < 2; ++g)
#pragma unroll
      for (int jk = 0; jk < 4; ++jk)
#pragma unroll
        for (int r = 0; r < 4; ++r) s[g][jk][r] = 0.0f;
    __builtin_amdgcn_s_setprio(1);
#pragma unroll
    for (int jk = 0; jk < 4; ++jk) {
      const short* kr = kt_base + (jk * 16 + row) * 64;
      bf16x8 a0 = *(const bf16x8*)(kr + c0s);
      bf16x8 a1 = *(const bf16x8*)(kr + c1s);
#pragma unroll
      for (int g = 0; g < 2; ++g) {
        s[g][jk] = __builtin_amdgcn_mfma_f32_16x16x32_bf16(a0, qb[g][0], s[g][jk], 0, 0, 0);
        s[g][jk] = __builtin_amdgcn_mfma_f32_16x16x32_bf16(a1, qb[g][1], s[g][jk], 0, 0, 0);
      }
    }
    __builtin_amdgcn_s_setprio(0);

    bf16x8 pb[2][2];
#pragma unroll
    for (int g = 0; g < 2; ++g) {
      float tj[4];
#pragma unroll
      for (int jk = 0; jk < 4; ++jk) {
#pragma unroll
        for (int r = 0; r < 4; ++r) s[g][jk][r] = exp2_(s[g][jk][r]);
        tj[jk] = (s[g][jk][0] + s[g][jk][1]) + (s[g][jk][2] + s[g][jk][3]);
      }
      l_[g] += (tj[0] + tj[1]) + (tj[2] + tj[3]);
#pragma unroll
      for (int c = 0; c < 2; ++c) {
        union { unsigned u[4]; bf16x8 v; } pu;
        pu.u[0] = pk2bf(s[g][2 * c][0], s[g][2 * c][1]);
        pu.u[1] = pk2bf(s[g][2 * c][2], s[g][2 * c][3]);
        pu.u[2] = pk2bf(s[g][2 * c + 1][0], s[g][2 * c + 1][1]);
        pu.u[3] = pk2bf(s[g][2 * c + 1][2], s[g][2 * c + 1][3]);
        pb[g][c] = pu.v;
      }
    }

    __builtin_amdgcn_s_setprio(1);
#pragma unroll
    for (int jd = 0; jd < 4; ++jd) {
      const short* vb = vt_base + (jd * 16 + row) * 72 + quad * 8;
#pragma unroll
      for (int c = 0; c < 2; ++c) {
        bf16x8 av = *(const bf16x8*)(vb + c * 32);
#pragma unroll
        for (int g = 0; g < 2; ++g)
          o[g][jd] = __builtin_amdgcn_mfma_f32_16x16x32_bf16(
              av, pb[g][c], o[g][jd], 0, 0, 0);
      }
    }
    __builtin_amdgcn_s_setprio(0);
  };

  { // prologue: tile 0 of both streams -> buffer 0
    stage_k(0, 0);
    bf16x8 a = *(const bf16x8*)(vbase + (size_t)sr0 * kN + sv * 2048 + sc0 * 8);
    bf16x8 b = *(const bf16x8*)(vbase + (size_t)sr1 * kN + sv * 2048 + sc1 * 8);
    stage_v(0, a, b);
  }
  __syncthreads();

  for (int kt = 0; kt < 32; ++kt) {
    const int cur = kt & 1;
    const bool more = (kt < 31);
    bf16x8 vn0, vn1;
    if (more) {
      stage_k(1 - cur, kt + 1);
      const int off = sv * 2048 + (kt + 1) * 64;
      vn0 = *(const bf16x8*)(vbase + (size_t)sr0 * kN + off + sc0 * 8);
      vn1 = *(const bf16x8*)(vbase + (size_t)sr1 * kN + off + sc1 * 8);
    }

    tile_step(&Kb[cur][ks][0], &VbS[cur][ks][0]);

    if (more) stage_v(1 - cur, vn0, vn1);
    __syncthreads();
  }

  // ---- combine key-halves via LDS overlay (barrier-protected), finalize ----
  float* Of = (float*)&Kb[0][0][0];    // 32 slots x 256 floats = 32 KB (exact)
  float* Lf = (float*)&VbS[0][0][0];   // 2 slots x 256 floats = 2 KB
  if (ks == 1) {
#pragma unroll
    for (int g = 0; g < 2; ++g) {
#pragma unroll
      for (int jd = 0; jd < 4; ++jd)
#pragma unroll
        for (int r = 0; r < 4; ++r)
          Of[(g * 16 + jd * 4 + r) * 256 + qg * 64 + lane] = o[g][jd][r];
      Lf[g * 256 + qg * 64 + lane] = l_[g];
    }
  }
  __syncthreads();
  if (ks == 0) {
#pragma unroll
    for (int g = 0; g < 2; ++g) {
#pragma unroll
      for (int jd = 0; jd < 4; ++jd)
#pragma unroll
        for (int r = 0; r < 4; ++r)
          o[g][jd][r] += Of[(g * 16 + jd * 4 + r) * 256 + qg * 64 + lane];
      l_[g] += Lf[g * 256 + qg * 64 + lane];
    }
    const int b_ = bh >> 3, h = bh & 7;
#pragma unroll
    for (int g = 0; g < 2; ++g) {
      float lt = l_[g];
      lt += __shfl_xor(lt, 16);
      lt += __shfl_xor(lt, 32);
      const float linv = 1.0f / lt;
      const int n_ = q0 + g * 16 + row;
      short* ob = attn + (size_t)(b_ * kN + n_) * kC + h * kHD + quad * 4;
#pragma unroll
      for (int jd = 0; jd < 4; ++jd) {
        short4 st = make_short4(f2bf(o[g][jd][0] * linv), f2bf(o[g][jd][1] * linv),
                                f2bf(o[g][jd][2] * linv), f2bf(o[g][jd][3] * linv));
        *(short4*)(ob + jd * 16) = st;
      }
    }
  }
}

// ---------------------------------------------------------------------------
// K4: out = [attn|cb] @ [Wa|Wo]^T, GEMM M=8192 N=512 K=1024 (K-concat),
// BK=64, XOR-source-swizzled staging.
// ---------------------------------------------------------------------------
template <typename TO>
__device__ __forceinline__ void out_body(
    const short* __restrict__ attn, const short* __restrict__ cb,
    const short* __restrict__ wb, TO* __restrict__ out) {
  __shared__ __align__(16) short As[128 * 64];  // 16 KB
  __shared__ __align__(16) short Bs[64 * 64];   //  8 KB
  const int t = threadIdx.x;
  const int wave = t >> 6, lane = t & 63;
  const int row = lane & 15, quad = lane >> 4;
  const int bn = blockIdx.x & 7;
  const int bm = blockIdx.x >> 3;
  const int m0 = bm * 128, n0 = bn * 64;
  const int wm = wave & 1, wn = wave >> 1;
  const int lrow = lane >> 3, lch = lane & 7;

  f32x4 acc[4][2];
#pragma unroll
  for (int mi = 0; mi < 4; ++mi)
#pragma unroll
    for (int ni = 0; ni < 2; ++ni)
#pragma unroll
      for (int r = 0; r < 4; ++r) acc[mi][ni][r] = 0.0f;

  const short* Wa = wb + 4 * kWElems;
  const short* Wo = wb + 5 * kWElems;

  for (int k0 = 0; k0 < 1024; k0 += 64) {
    const short* Asrc = (k0 < 512) ? attn : cb;
    const short* Bsrc = (k0 < 512) ? Wa : Wo;
    const int ka = k0 & 511;
#pragma unroll
    for (int p = 0; p < 4; ++p) {
      const int m = wave * 32 + p * 8 + lrow;
      const int kch = lch ^ (m & 7);
      gload_lds16(Asrc + (size_t)(m0 + m) * kC + ka + kch * 8,
                  &As[(wave * 32 + p * 8) * 64]);
    }
#pragma unroll
    for (int p = 0; p < 2; ++p) {
      const int n = wave * 16 + p * 8 + lrow;
      const int kch = lch ^ (n & 7);
      gload_lds16(Bsrc + (size_t)(n0 + n) * kC + ka + kch * 8,
                  &Bs[(wave * 16 + p * 8) * 64]);
    }
    __syncthreads();

#pragma unroll
    for (int kk2 = 0; kk2 < 2; ++kk2) {
      bf16x8 af[4], bfr[2];
#pragma unroll
      for (int mi = 0; mi < 4; ++mi) {
        const int m = wm * 64 + mi * 16 + row;
        const int ch = (kk2 * 4 + quad) ^ (m & 7);
        af[mi] = *(const bf16x8*)(&As[m * 64 + ch * 8]);
      }
#pragma unroll
      for (int ni = 0; ni < 2; ++ni) {
        const int n = wn * 32 + ni * 16 + row;
        const int ch = (kk2 * 4 + quad) ^ (n & 7);
        bfr[ni] = *(const bf16x8*)(&Bs[n * 64 + ch * 8]);
      }
#pragma unroll
      for (int mi = 0; mi < 4; ++mi)
#pragma unroll
        for (int ni = 0; ni < 2; ++ni)
          acc[mi][ni] = __builtin_amdgcn_mfma_f32_16x16x32_bf16(
              af[mi], bfr[ni], acc[mi][ni], 0, 0, 0);
    }
    __syncthreads();
  }

#pragma unroll
  for (int mi = 0; mi < 4; ++mi)
#pragma unroll
    for (int ni = 0; ni < 2; ++ni)
#pragma unroll
      for (int r = 0; r < 4; ++r) {
        const int gm = m0 + wm * 64 + mi * 16 + quad * 4 + r;
        const int gc = n0 + wn * 32 + ni * 16 + row;
        stf(out + (size_t)gm * kC + gc, acc[mi][ni][r]);
      }
}

__global__ __launch_bounds__(256, 4) void out_gemm(
    const short* __restrict__ attn, const short* __restrict__ cb,
    const short* __restrict__ wb, const int* __restrict__ flag, void* out) {
  if (*flag)
    out_body<short>(attn, cb, wb, (short*)out);
  else
    out_body<float>(attn, cb, wb, (float*)out);
}

extern "C" void kernel_launch(void* const* d_in, const int* in_sizes, int n_in,
                              void* d_out, int out_size, void* d_ws, size_t ws_size,
                              hipStream_t stream) {
  const void* x   = d_in[0];
  const void* Wq  = d_in[1];
  const void* Wk  = d_in[2];
  const void* Wv  = d_in[3];
  const void* Wa  = d_in[4];
  const void* Wc  = d_in[5];
  const void* dwk = d_in[6];
  const void* dwb = d_in[7];
  const void* Wco = d_in[8];

  short* ws = (short*)d_ws;
  const size_t E = (size_t)kBN * kC;
  int*   flag = (int*)ws;
  short* wb   = ws + 256;
  short* q    = wb + kWAll + kWExtra;
  short* k    = q + E;
  short* vT   = k + E;
  short* ci   = vT + E;
  short* cb   = ci + E;
  short* attn = ci;   // attn overwrites ci (consumed by dwconv first)
  short* xb   = cb;   // consumed by proj_gemm before dwconv writes cb

  detect_dtype<<<1, 64, 0, stream>>>((const unsigned*)x, flag);
  const int cvt_threads = kW8 + kWExtra + kX8;
  convert_all<<<(cvt_threads + 255) / 256, 256, 0, stream>>>(
      Wq, Wk, Wv, Wc, Wa, Wco, dwk, dwb, x, flag, wb, xb);
  proj_gemm<<<1024, 256, 0, stream>>>(xb, wb, q, k, vT, ci);
  dwconv<<<(kBN * kC) / (256 * 8), 256, 0, stream>>>(ci, wb, cb);
  attn_flash<<<512, 512, 0, stream>>>(q, k, vT, attn);
  out_gemm<<<512, 256, 0, stream>>>(attn, cb, wb, flag, d_out);
}

// Round 6
// 222.555 us; speedup vs baseline: 1.2369x; 1.1044x over previous
//
#include <hip/hip_runtime.h>

typedef __attribute__((ext_vector_type(8))) short bf16x8;
typedef __attribute__((ext_vector_type(4))) float f32x4;

constexpr int kB = 2, kN = 4096, kC = 512, kNH = 8, kHD = 64;
constexpr int kBN = kB * kN;                 // 8192
constexpr int kWElems = 262144;              // 512*512
constexpr int kWAll = 6 * kWElems;           // 6 weight matrices
constexpr int kWExtra = 3584;                // dwk(1536) + dwb(512) + dwkT(1536)
constexpr float kQScale = 0.1803368801f;     // (1/8) * log2(e)

__device__ __forceinline__ short f2bf(float f) {
  union { float f; unsigned u; } v; v.f = f;
  unsigned r = v.u + 0x7fffu + ((v.u >> 16) & 1u);
  return (short)(r >> 16);
}
__device__ __forceinline__ float bf2f(short s) {
  union { unsigned u; float f; } v; v.u = ((unsigned)(unsigned short)s) << 16;
  return v.f;
}
__device__ __forceinline__ float exp2_(float x) {
#if __has_builtin(__builtin_amdgcn_exp2f)
  return __builtin_amdgcn_exp2f(x);
#else
  return exp2f(x);
#endif
}
// pack two f32 -> two bf16 (round-half-up) in one dword via v_perm
__device__ __forceinline__ unsigned pk2bf(float a, float b) {
  union { float f; unsigned u; } ua, ub; ua.f = a; ub.f = b;
#if __has_builtin(__builtin_amdgcn_perm)
  return __builtin_amdgcn_perm(ub.u + 0x8000u, ua.u + 0x8000u, 0x07060302u);
#else
  return ((ua.u + 0x8000u) >> 16) | (((ub.u + 0x8000u) >> 16) << 16);
#endif
}

__device__ __forceinline__ bf16x8 ld8(const short* p) { return *(const bf16x8*)p; }
__device__ __forceinline__ bf16x8 ld8(const float* p) {
  float4 a = *(const float4*)p;
  float4 b = *(const float4*)(p + 4);
  bf16x8 r;
  r[0] = f2bf(a.x); r[1] = f2bf(a.y); r[2] = f2bf(a.z); r[3] = f2bf(a.w);
  r[4] = f2bf(b.x); r[5] = f2bf(b.y); r[6] = f2bf(b.z); r[7] = f2bf(b.w);
  return r;
}

// async 16B global->LDS (LDS dest wave-uniform base + 16*lane).
__device__ __forceinline__ void gload_lds16(const void* g, void* l) {
  __builtin_amdgcn_global_load_lds(
      (const __attribute__((address_space(1))) void*)g,
      (__attribute__((address_space(3))) void*)l, 16, 0, 0);
}

// K0: classify input dtype on-device.
__global__ void detect_dtype(const unsigned* __restrict__ x, int* __restrict__ flag) {
  const int lane = threadIdx.x & 63;
  unsigned w = x[lane];
  int e = (int)((w >> 7) & 0xffu);
  bool bf = (e >= 100 && e <= 140);
  unsigned long long m = __ballot(bf);
  if (lane == 0) *flag = (__popcll(m) >= 32) ? 1 : 0;
}

// K0b: weights AND x -> bf16 in one launch.
// dst layout: [Wq,Wk,Wv,Wc,Wa,Wco | dwk 1536 | dwb 512 | dwkT 3x512]; xb separate.
constexpr int kW8 = kWAll / 8;        // 196608
constexpr int kX8 = kBN * kC / 8;     // 524288
__global__ __launch_bounds__(256) void convert_all(
    const void* Wq, const void* Wk, const void* Wv, const void* Wc,
    const void* Wa, const void* Wco, const void* dwk, const void* dwb,
    const void* x, const int* __restrict__ flag, short* __restrict__ dst,
    short* __restrict__ xb) {
  const int gtid = blockIdx.x * 256 + threadIdx.x;
  const bool bf = (*flag != 0);
  if (gtid < kW8) {
    const int e = gtid * 8;
    const int t = e >> 18, off = e & (kWElems - 1);
    const void* src = (t == 0) ? Wq : (t == 1) ? Wk : (t == 2) ? Wv
                    : (t == 3) ? Wc : (t == 4) ? Wa : Wco;
    bf16x8 v = bf ? ld8((const short*)src + off) : ld8((const float*)src + off);
    *(bf16x8*)(dst + e) = v;
  } else if (gtid < kW8 + kWExtra) {
    const int eoff = gtid - kW8;
    if (eoff < 1536) {
      dst[kWAll + eoff] = bf ? ((const short*)dwk)[eoff]
                             : f2bf(((const float*)dwk)[eoff]);
    } else if (eoff < 2048) {
      const int i = eoff - 1536;
      dst[kWAll + 1536 + i] = bf ? ((const short*)dwb)[i]
                                 : f2bf(((const float*)dwb)[i]);
    } else {
      const int t2 = eoff - 2048;
      const int tap = t2 >> 9, c = t2 & 511;
      dst[kWAll + 2048 + t2] = bf ? ((const short*)dwk)[c * 3 + tap]
                                  : f2bf(((const float*)dwk)[c * 3 + tap]);
    }
  } else if (gtid < kW8 + kWExtra + kX8) {
    const int e = (gtid - kW8 - kWExtra) * 8;
    bf16x8 v = bf ? ld8((const short*)x + e) : ld8((const float*)x + e);
    *(bf16x8*)(xb + e) = v;
  }
}

// ---------------------------------------------------------------------------
// K1: fused input projection GEMM [8192x512] x [2048x512]^T.
// BK=64, XOR-source-swizzled staging. LDS-bounce epilogue: acc -> swizzled
// 32KB LDS tile (transposed for the vT output), then coalesced b128 stores.
// ---------------------------------------------------------------------------
__global__ __launch_bounds__(256, 3) void proj_gemm(
    const short* __restrict__ xb, const short* __restrict__ wb,
    short* __restrict__ q, short* __restrict__ k, short* __restrict__ vT,
    short* __restrict__ ci) {
  __shared__ __align__(16) short Sh[16384];     // 32 KB: As | Bs, reused by epilogue
  short* As = Sh;                               // 128*64
  short* Bs = Sh + 8192;                        // 128*64
  const int t = threadIdx.x;
  const int wave = t >> 6, lane = t & 63;
  const int row = lane & 15, quad = lane >> 4;
  const int bn = blockIdx.x & 15;
  const int bm = blockIdx.x >> 4;
  const int m0 = bm * 128, n0 = bn * 128;
  const int wm = wave & 1, wn = wave >> 1;
  const int lrow = lane >> 3, lch = lane & 7;   // staging: 8 rows x 8 chunks

  f32x4 acc[4][4];
#pragma unroll
  for (int mi = 0; mi < 4; ++mi)
#pragma unroll
    for (int ni = 0; ni < 4; ++ni)
#pragma unroll
      for (int r = 0; r < 4; ++r) acc[mi][ni][r] = 0.0f;

  for (int k0 = 0; k0 < kC; k0 += 64) {
#pragma unroll
    for (int p = 0; p < 4; ++p) {
      const int m = wave * 32 + p * 8 + lrow;     // tile row this lane stages
      const int kch = lch ^ (m & 7);              // swizzled source chunk
      gload_lds16(xb + (size_t)(m0 + m) * kC + k0 + kch * 8,
                  &As[(wave * 32 + p * 8) * 64]);
      gload_lds16(wb + (size_t)(n0 + m) * kC + k0 + kch * 8,
                  &Bs[(wave * 32 + p * 8) * 64]);
    }
    __syncthreads();

#pragma unroll
    for (int kk2 = 0; kk2 < 2; ++kk2) {
      bf16x8 af[4], bfr[4];
#pragma unroll
      for (int mi = 0; mi < 4; ++mi) {
        const int m = wm * 64 + mi * 16 + row;
        const int ch = (kk2 * 4 + quad) ^ (m & 7);
        af[mi] = *(const bf16x8*)(&As[m * 64 + ch * 8]);
      }
#pragma unroll
      for (int ni = 0; ni < 4; ++ni) {
        const int n = wn * 64 + ni * 16 + row;
        const int ch = (kk2 * 4 + quad) ^ (n & 7);
        bfr[ni] = *(const bf16x8*)(&Bs[n * 64 + ch * 8]);
      }
#pragma unroll
      for (int mi = 0; mi < 4; ++mi)
#pragma unroll
        for (int ni = 0; ni < 4; ++ni)
          acc[mi][ni] = __builtin_amdgcn_mfma_f32_16x16x32_bf16(
              af[mi], bfr[ni], acc[mi][ni], 0, 0, 0);
    }
    __syncthreads();
  }

  // ---- epilogue: LDS bounce -> coalesced stores ----
  // Block's 128-channel span lies in exactly one mat (128 | 512).
  const int mat = n0 >> 9;
  const float scale = (mat == 0) ? kQScale : 1.0f;
  if (mat != 2) {
    // Ep[token m][chan n], 16B-chunk XOR swizzle (slot = (n>>3)^(m&15))
#pragma unroll
    for (int mi = 0; mi < 4; ++mi)
#pragma unroll
      for (int ni = 0; ni < 4; ++ni)
#pragma unroll
        for (int r = 0; r < 4; ++r) {
          const int m = wm * 64 + mi * 16 + quad * 4 + r;
          const int n = wn * 64 + ni * 16 + row;
          Sh[m * 128 + (((n >> 3) ^ (m & 15)) * 8) + (n & 7)] =
              f2bf(acc[mi][ni][r] * scale);
        }
  } else {
    // vT output: store transposed Ep[chan n][token m]
#pragma unroll
    for (int mi = 0; mi < 4; ++mi)
#pragma unroll
      for (int ni = 0; ni < 4; ++ni)
#pragma unroll
        for (int r = 0; r < 4; ++r) {
          const int m = wm * 64 + mi * 16 + quad * 4 + r;
          const int n = wn * 64 + ni * 16 + row;
          Sh[n * 128 + (((m >> 3) ^ (n & 15)) * 8) + (m & 7)] =
              f2bf(acc[mi][ni][r]);
        }
  }
  __syncthreads();
  const int b_ = m0 >> 12;                    // batch index (tokens 4096/batch)
  const int rsub = lane >> 4, chk = lane & 15;
#pragma unroll
  for (int i = 0; i < 8; ++i) {
    const int rr = i * 16 + wave * 4 + rsub;  // Ep row (token, or chan for vT)
    bf16x8 v = *(const bf16x8*)(&Sh[rr * 128 + ((chk ^ (rr & 15)) * 8)]);
    if (mat == 2) {
      const int cg = (n0 + rr) & 511;
      const int h = cg >> 6, d = cg & 63;
      const int nb = (m0 & (kN - 1)) + chk * 8;
      *(bf16x8*)(vT + ((size_t)((b_ * kNH + h) * kHD + d)) * kN + nb) = v;
    } else {
      const int n_ = (m0 & (kN - 1)) + rr;
      const int cg = (n0 + chk * 8) & 511;
      if (mat == 3) {
        *(bf16x8*)(ci + ((size_t)(b_ * kN + n_)) * kC + cg) = v;
      } else {
        const int h = cg >> 6, d = cg & 63;
        short* dst = (mat == 0) ? q : k;
        *(bf16x8*)(dst + ((size_t)((b_ * kNH + h) * kN + n_)) * kHD + d) = v;
      }
    }
  }
}

// K2: depthwise conv, vectorized bf16x8 (uses dwkT + dwb from wb).
__global__ __launch_bounds__(256) void dwconv(
    const short* __restrict__ ci, const short* __restrict__ wb,
    short* __restrict__ cb) {
  const int e0 = (blockIdx.x * 256 + threadIdx.x) * 8;
  const int c0 = e0 & (kC - 1);
  const int bn = e0 >> 9;
  const int n_ = bn & (kN - 1);
  bf16x8 xc = ld8(ci + e0);
  bf16x8 xm, xp;
  if (n_ > 0) xm = ld8(ci + e0 - kC);
  else
#pragma unroll
    for (int i = 0; i < 8; ++i) xm[i] = 0;
  if (n_ < kN - 1) xp = ld8(ci + e0 + kC);
  else
#pragma unroll
    for (int i = 0; i < 8; ++i) xp[i] = 0;
  bf16x8 w0 = ld8(wb + kWAll + 2048 + c0);
  bf16x8 w1 = ld8(wb + kWAll + 2048 + 512 + c0);
  bf16x8 w2 = ld8(wb + kWAll + 2048 + 1024 + c0);
  bf16x8 bi = ld8(wb + kWAll + 1536 + c0);
  bf16x8 o;
#pragma unroll
  for (int i = 0; i < 8; ++i) {
    float a = bf2f(bi[i]) + bf2f(xm[i]) * bf2f(w0[i]) +
              bf2f(xc[i]) * bf2f(w1[i]) + bf2f(xp[i]) * bf2f(w2[i]);
    o[i] = f2bf(a);
  }
  *(bf16x8*)(cb + e0) = o;
}

// ---------------------------------------------------------------------------
// K3: flash attention v8.1 — v8 (in-block key-split, passed R4) + zero-C
// first MFMA (no per-tile acc re-zeroing).
// ---------------------------------------------------------------------------
__global__ __launch_bounds__(512, 4) void attn_flash(
    const short* __restrict__ q, const short* __restrict__ k,
    const short* __restrict__ vT, short* __restrict__ attn) {
  __shared__ __align__(16) short Kb[2][2][64 * 64];    // [buf][ks] 32 KB
  __shared__ __align__(16) short VbS[2][2][64 * 72];   // [buf][ks] 36 KB
  const int t = threadIdx.x;
  const int wave = t >> 6;           // 0..7
  const int lane = t & 63;
  const int row = lane & 15;
  const int quad = lane >> 4;
  const int qg = wave & 3;           // q-group (32 rows each)
  const int ks = wave >> 2;          // key-stream

  const int slot = blockIdx.x & 7;
  const int inner = blockIdx.x >> 3;          // 0..63
  const int bh = slot * 2 + (inner & 1);
  const int q0 = (inner >> 1) * 128 + qg * 32;

  const short* qbase = q + (size_t)(bh * kN + q0) * kHD;
  const short* kbase = k + (size_t)bh * kN * kHD;
  const short* vbase = vT + (size_t)bh * kHD * kN;

  bf16x8 qb[2][2];
#pragma unroll
  for (int g = 0; g < 2; ++g) {
    qb[g][0] = *(const bf16x8*)(qbase + (g * 16 + row) * kHD + quad * 8);
    qb[g][1] = *(const bf16x8*)(qbase + (g * 16 + row) * kHD + 32 + quad * 8);
  }

  const f32x4 z4 = {0.0f, 0.0f, 0.0f, 0.0f};   // persistent zero C-block

  f32x4 o[2][4];   // O^T partial accumulators (this wave's key half)
#pragma unroll
  for (int g = 0; g < 2; ++g)
#pragma unroll
    for (int j = 0; j < 4; ++j)
#pragma unroll
      for (int r = 0; r < 4; ++r) o[g][j][r] = 0.0f;
  float l_[2] = {0.0f, 0.0f};

  // K staging (gload_lds): XOR-source swizzle, read side XORs back.
  const int ksrow = lane >> 3;
  const int kschunk = (lane & 7) ^ ksrow;
  auto stage_k = [&](int buf, int kt) {
#pragma unroll
    for (int s2 = 0; s2 < 2; ++s2)
      gload_lds16(
          kbase + (size_t)(s2 * 2048 + kt * 64 + wave * 8 + ksrow) * 64 +
              kschunk * 8,
          &Kb[buf][s2][wave * 512]);
  };

  // V staging: threads 0-255 stage stream-0 tile, 256-511 stream-1 tile.
  const int sv = t >> 8;
  const int ii = t & 255;
  const int i0 = ii, i1 = ii + 256;
  const int sr0 = i0 >> 3, sc0 = i0 & 7;
  const int sr1 = i1 >> 3, sc1 = i1 & 7;
  const int vb0 = (sc0 >> 2) * 32 + (sc0 & 1) * 16 + (sc0 & 2) * 2;
  const int vb1 = (sc1 >> 2) * 32 + (sc1 & 1) * 16 + (sc1 & 2) * 2;

  auto stage_v = [&](int buf, bf16x8 v0, bf16x8 v1) {
    *(short4*)(&VbS[buf][sv][sr0 * 72 + vb0]) =
        make_short4(v0[0], v0[1], v0[2], v0[3]);
    *(short4*)(&VbS[buf][sv][sr0 * 72 + vb0 + 8]) =
        make_short4(v0[4], v0[5], v0[6], v0[7]);
    *(short4*)(&VbS[buf][sv][sr1 * 72 + vb1]) =
        make_short4(v1[0], v1[1], v1[2], v1[3]);
    *(short4*)(&VbS[buf][sv][sr1 * 72 + vb1 + 8]) =
        make_short4(v1[4], v1[5], v1[6], v1[7]);
  };

  // fragment-read chunk offsets (constant per lane)
  const int c0s = ((quad) ^ (row & 7)) * 8;
  const int c1s = ((quad + 4) ^ (row & 7)) * 8;

  // per-tile compute: QK -> softmax -> PV
  auto tile_step = [&](const short* kt_base, const short* vt_base) {
    f32x4 s[2][4];
    __builtin_amdgcn_s_setprio(1);
#pragma unroll
    for (int jk = 0; jk < 4; ++jk) {
      const short* kr = kt_base + (jk * 16 + row) * 64;
      bf16x8 a0 = *(const bf16x8*)(kr + c0s);
      bf16x8 a1 = *(const bf16x8*)(kr + c1s);
#pragma unroll
      for (int g = 0; g < 2; ++g) {
        s[g][jk] = __builtin_amdgcn_mfma_f32_16x16x32_bf16(a0, qb[g][0], z4, 0, 0, 0);
        s[g][jk] = __builtin_amdgcn_mfma_f32_16x16x32_bf16(a1, qb[g][1], s[g][jk], 0, 0, 0);
      }
    }
    __builtin_amdgcn_s_setprio(0);

    bf16x8 pb[2][2];
#pragma unroll
    for (int g = 0; g < 2; ++g) {
      float tj[4];
#pragma unroll
      for (int jk = 0; jk < 4; ++jk) {
#pragma unroll
        for (int r = 0; r < 4; ++r) s[g][jk][r] = exp2_(s[g][jk][r]);
        tj[jk] = (s[g][jk][0] + s[g][jk][1]) + (s[g][jk][2] + s[g][jk][3]);
      }
      l_[g] += (tj[0] + tj[1]) + (tj[2] + tj[3]);
#pragma unroll
      for (int c = 0; c < 2; ++c) {
        union { unsigned u[4]; bf16x8 v; } pu;
        pu.u[0] = pk2bf(s[g][2 * c][0], s[g][2 * c][1]);
        pu.u[1] = pk2bf(s[g][2 * c][2], s[g][2 * c][3]);
        pu.u[2] = pk2bf(s[g][2 * c + 1][0], s[g][2 * c + 1][1]);
        pu.u[3] = pk2bf(s[g][2 * c + 1][2], s[g][2 * c + 1][3]);
        pb[g][c] = pu.v;
      }
    }

    __builtin_amdgcn_s_setprio(1);
#pragma unroll
    for (int jd = 0; jd < 4; ++jd) {
      const short* vb = vt_base + (jd * 16 + row) * 72 + quad * 8;
#pragma unroll
      for (int c = 0; c < 2; ++c) {
        bf16x8 av = *(const bf16x8*)(vb + c * 32);
#pragma unroll
        for (int g = 0; g < 2; ++g)
          o[g][jd] = __builtin_amdgcn_mfma_f32_16x16x32_bf16(
              av, pb[g][c], o[g][jd], 0, 0, 0);
      }
    }
    __builtin_amdgcn_s_setprio(0);
  };

  { // prologue: tile 0 of both streams -> buffer 0
    stage_k(0, 0);
    bf16x8 a = *(const bf16x8*)(vbase + (size_t)sr0 * kN + sv * 2048 + sc0 * 8);
    bf16x8 b = *(const bf16x8*)(vbase + (size_t)sr1 * kN + sv * 2048 + sc1 * 8);
    stage_v(0, a, b);
  }
  __syncthreads();

  for (int kt = 0; kt < 32; ++kt) {
    const int cur = kt & 1;
    const bool more = (kt < 31);
    bf16x8 vn0, vn1;
    if (more) {
      stage_k(1 - cur, kt + 1);
      const int off = sv * 2048 + (kt + 1) * 64;
      vn0 = *(const bf16x8*)(vbase + (size_t)sr0 * kN + off + sc0 * 8);
      vn1 = *(const bf16x8*)(vbase + (size_t)sr1 * kN + off + sc1 * 8);
    }

    tile_step(&Kb[cur][ks][0], &VbS[cur][ks][0]);

    if (more) stage_v(1 - cur, vn0, vn1);
    __syncthreads();
  }

  // ---- combine key-halves via LDS overlay (barrier-protected), finalize ----
  float* Of = (float*)&Kb[0][0][0];    // 32 slots x 256 floats = 32 KB (exact)
  float* Lf = (float*)&VbS[0][0][0];   // 2 slots x 256 floats = 2 KB
  if (ks == 1) {
#pragma unroll
    for (int g = 0; g < 2; ++g) {
#pragma unroll
      for (int jd = 0; jd < 4; ++jd)
#pragma unroll
        for (int r = 0; r < 4; ++r)
          Of[(g * 16 + jd * 4 + r) * 256 + qg * 64 + lane] = o[g][jd][r];
      Lf[g * 256 + qg * 64 + lane] = l_[g];
    }
  }
  __syncthreads();
  if (ks == 0) {
#pragma unroll
    for (int g = 0; g < 2; ++g) {
#pragma unroll
      for (int jd = 0; jd < 4; ++jd)
#pragma unroll
        for (int r = 0; r < 4; ++r)
          o[g][jd][r] += Of[(g * 16 + jd * 4 + r) * 256 + qg * 64 + lane];
      l_[g] += Lf[g * 256 + qg * 64 + lane];
    }
    const int b_ = bh >> 3, h = bh & 7;
#pragma unroll
    for (int g = 0; g < 2; ++g) {
      float lt = l_[g];
      lt += __shfl_xor(lt, 16);
      lt += __shfl_xor(lt, 32);
      const float linv = 1.0f / lt;
      const int n_ = q0 + g * 16 + row;
      short* ob = attn + (size_t)(b_ * kN + n_) * kC + h * kHD + quad * 4;
#pragma unroll
      for (int jd = 0; jd < 4; ++jd) {
        short4 st = make_short4(f2bf(o[g][jd][0] * linv), f2bf(o[g][jd][1] * linv),
                                f2bf(o[g][jd][2] * linv), f2bf(o[g][jd][3] * linv));
        *(short4*)(ob + jd * 16) = st;
      }
    }
  }
}

// ---------------------------------------------------------------------------
// K4: out = [attn|cb] @ [Wa|Wo]^T, GEMM M=8192 N=512 K=1024 (K-concat),
// BK=64, XOR-source-swizzled staging. LDS-bounce epilogue (f32 and bf16).
// ---------------------------------------------------------------------------
template <typename TO>
__device__ __forceinline__ void out_body(
    const short* __restrict__ attn, const short* __restrict__ cb,
    const short* __restrict__ wb, TO* __restrict__ out) {
  __shared__ __align__(16) short Sh[16384];     // 32 KB: As | Bs | epilogue
  short* As = Sh;                               // 128*64
  short* Bs = Sh + 8192;                        // 64*64
  const int t = threadIdx.x;
  const int wave = t >> 6, lane = t & 63;
  const int row = lane & 15, quad = lane >> 4;
  const int bn = blockIdx.x & 7;
  const int bm = blockIdx.x >> 3;
  const int m0 = bm * 128, n0 = bn * 64;
  const int wm = wave & 1, wn = wave >> 1;
  const int lrow = lane >> 3, lch = lane & 7;

  f32x4 acc[4][2];
#pragma unroll
  for (int mi = 0; mi < 4; ++mi)
#pragma unroll
    for (int ni = 0; ni < 2; ++ni)
#pragma unroll
      for (int r = 0; r < 4; ++r) acc[mi][ni][r] = 0.0f;

  const short* Wa = wb + 4 * kWElems;
  const short* Wo = wb + 5 * kWElems;

  for (int k0 = 0; k0 < 1024; k0 += 64) {
    const short* Asrc = (k0 < 512) ? attn : cb;
    const short* Bsrc = (k0 < 512) ? Wa : Wo;
    const int ka = k0 & 511;
#pragma unroll
    for (int p = 0; p < 4; ++p) {
      const int m = wave * 32 + p * 8 + lrow;
      const int kch = lch ^ (m & 7);
      gload_lds16(Asrc + (size_t)(m0 + m) * kC + ka + kch * 8,
                  &As[(wave * 32 + p * 8) * 64]);
    }
#pragma unroll
    for (int p = 0; p < 2; ++p) {
      const int n = wave * 16 + p * 8 + lrow;
      const int kch = lch ^ (n & 7);
      gload_lds16(Bsrc + (size_t)(n0 + n) * kC + ka + kch * 8,
                  &Bs[(wave * 16 + p * 8) * 64]);
    }
    __syncthreads();

#pragma unroll
    for (int kk2 = 0; kk2 < 2; ++kk2) {
      bf16x8 af[4], bfr[2];
#pragma unroll
      for (int mi = 0; mi < 4; ++mi) {
        const int m = wm * 64 + mi * 16 + row;
        const int ch = (kk2 * 4 + quad) ^ (m & 7);
        af[mi] = *(const bf16x8*)(&As[m * 64 + ch * 8]);
      }
#pragma unroll
      for (int ni = 0; ni < 2; ++ni) {
        const int n = wn * 32 + ni * 16 + row;
        const int ch = (kk2 * 4 + quad) ^ (n & 7);
        bfr[ni] = *(const bf16x8*)(&Bs[n * 64 + ch * 8]);
      }
#pragma unroll
      for (int mi = 0; mi < 4; ++mi)
#pragma unroll
        for (int ni = 0; ni < 2; ++ni)
          acc[mi][ni] = __builtin_amdgcn_mfma_f32_16x16x32_bf16(
              af[mi], bfr[ni], acc[mi][ni], 0, 0, 0);
    }
    __syncthreads();
  }

  // ---- epilogue: LDS bounce -> coalesced 16B stores ----
  if constexpr (sizeof(TO) == 4) {
    float* Shf = (float*)Sh;   // 128 x 64 f32 = 32 KB (exact)
#pragma unroll
    for (int mi = 0; mi < 4; ++mi)
#pragma unroll
      for (int ni = 0; ni < 2; ++ni)
#pragma unroll
        for (int r = 0; r < 4; ++r) {
          const int m = wm * 64 + mi * 16 + quad * 4 + r;
          const int n = wn * 32 + ni * 16 + row;
          Shf[m * 64 + (((n >> 2) ^ (m & 15)) * 4) + (n & 3)] = acc[mi][ni][r];
        }
    __syncthreads();
    const int rsub = lane >> 4, chk = lane & 15;
#pragma unroll
    for (int i = 0; i < 8; ++i) {
      const int rr = i * 16 + wave * 4 + rsub;
      float4 v = *(const float4*)(&Shf[rr * 64 + ((chk ^ (rr & 15)) * 4)]);
      *(float4*)((float*)out + (size_t)(m0 + rr) * kC + n0 + chk * 4) = v;
    }
  } else {
#pragma unroll
    for (int mi = 0; mi < 4; ++mi)
#pragma unroll
      for (int ni = 0; ni < 2; ++ni)
#pragma unroll
        for (int r = 0; r < 4; ++r) {
          const int m = wm * 64 + mi * 16 + quad * 4 + r;
          const int n = wn * 32 + ni * 16 + row;
          Sh[m * 64 + (((n >> 3) ^ (m & 7)) * 8) + (n & 7)] =
              f2bf(acc[mi][ni][r]);
        }
    __syncthreads();
    const int rsub = lane >> 3, chk = lane & 7;
#pragma unroll
    for (int i = 0; i < 4; ++i) {
      const int rr = i * 32 + wave * 8 + rsub;
      bf16x8 v = *(const bf16x8*)(&Sh[rr * 64 + ((chk ^ (rr & 7)) * 8)]);
      *(bf16x8*)((short*)out + (size_t)(m0 + rr) * kC + n0 + chk * 8) = v;
    }
  }
}

__global__ __launch_bounds__(256, 4) void out_gemm(
    const short* __restrict__ attn, const short* __restrict__ cb,
    const short* __restrict__ wb, const int* __restrict__ flag, void* out) {
  if (*flag)
    out_body<short>(attn, cb, wb, (short*)out);
  else
    out_body<float>(attn, cb, wb, (float*)out);
}

extern "C" void kernel_launch(void* const* d_in, const int* in_sizes, int n_in,
                              void* d_out, int out_size, void* d_ws, size_t ws_size,
                              hipStream_t stream) {
  const void* x   = d_in[0];
  const void* Wq  = d_in[1];
  const void* Wk  = d_in[2];
  const void* Wv  = d_in[3];
  const void* Wa  = d_in[4];
  const void* Wc  = d_in[5];
  const void* dwk = d_in[6];
  const void* dwb = d_in[7];
  const void* Wco = d_in[8];

  short* ws = (short*)d_ws;
  const size_t E = (size_t)kBN * kC;
  int*   flag = (int*)ws;
  short* wb   = ws + 256;
  short* q    = wb + kWAll + kWExtra;
  short* k    = q + E;
  short* vT   = k + E;
  short* ci   = vT + E;
  short* cb   = ci + E;
  short* attn = ci;   // attn overwrites ci (consumed by dwconv first)
  short* xb   = cb;   // consumed by proj_gemm before dwconv writes cb

  detect_dtype<<<1, 64, 0, stream>>>((const unsigned*)x, flag);
  const int cvt_threads = kW8 + kWExtra + kX8;
  convert_all<<<(cvt_threads + 255) / 256, 256, 0, stream>>>(
      Wq, Wk, Wv, Wc, Wa, Wco, dwk, dwb, x, flag, wb, xb);
  proj_gemm<<<1024, 256, 0, stream>>>(xb, wb, q, k, vT, ci);
  dwconv<<<(kBN * kC) / (256 * 8), 256, 0, stream>>>(ci, wb, cb);
  attn_flash<<<512, 512, 0, stream>>>(q, k, vT, attn);
  out_gemm<<<512, 256, 0, stream>>>(attn, cb, wb, flag, d_out);
}

// Round 7
// 214.942 us; speedup vs baseline: 1.2807x; 1.0354x over previous
//
#include <hip/hip_runtime.h>

typedef __attribute__((ext_vector_type(8))) short bf16x8;
typedef __attribute__((ext_vector_type(4))) float f32x4;

constexpr int kB = 2, kN = 4096, kC = 512, kNH = 8, kHD = 64;
constexpr int kBN = kB * kN;                 // 8192
constexpr int kWElems = 262144;              // 512*512
constexpr int kWAll = 6 * kWElems;           // 6 weight matrices
constexpr int kWExtra = 3584;                // dwk(1536) + dwb(512) + dwkT(1536)
constexpr float kQScale = 0.1803368801f;     // (1/8) * log2(e)

__device__ __forceinline__ short f2bf(float f) {
  union { float f; unsigned u; } v; v.f = f;
  unsigned r = v.u + 0x7fffu + ((v.u >> 16) & 1u);
  return (short)(r >> 16);
}
__device__ __forceinline__ float bf2f(short s) {
  union { unsigned u; float f; } v; v.u = ((unsigned)(unsigned short)s) << 16;
  return v.f;
}
__device__ __forceinline__ float exp2_(float x) {
#if __has_builtin(__builtin_amdgcn_exp2f)
  return __builtin_amdgcn_exp2f(x);
#else
  return exp2f(x);
#endif
}
// pack two f32 -> two bf16 (round-half-up) in one dword via v_perm
__device__ __forceinline__ unsigned pk2bf(float a, float b) {
  union { float f; unsigned u; } ua, ub; ua.f = a; ub.f = b;
#if __has_builtin(__builtin_amdgcn_perm)
  return __builtin_amdgcn_perm(ub.u + 0x8000u, ua.u + 0x8000u, 0x07060302u);
#else
  return ((ua.u + 0x8000u) >> 16) | (((ub.u + 0x8000u) >> 16) << 16);
#endif
}

__device__ __forceinline__ bf16x8 ld8(const short* p) { return *(const bf16x8*)p; }
__device__ __forceinline__ bf16x8 ld8(const float* p) {
  float4 a = *(const float4*)p;
  float4 b = *(const float4*)(p + 4);
  bf16x8 r;
  r[0] = f2bf(a.x); r[1] = f2bf(a.y); r[2] = f2bf(a.z); r[3] = f2bf(a.w);
  r[4] = f2bf(b.x); r[5] = f2bf(b.y); r[6] = f2bf(b.z); r[7] = f2bf(b.w);
  return r;
}

// async 16B global->LDS (LDS dest wave-uniform base + 16*lane).
__device__ __forceinline__ void gload_lds16(const void* g, void* l) {
  __builtin_amdgcn_global_load_lds(
      (const __attribute__((address_space(1))) void*)g,
      (__attribute__((address_space(3))) void*)l, 16, 0, 0);
}

// K0: classify input dtype on-device.
__global__ void detect_dtype(const unsigned* __restrict__ x, int* __restrict__ flag) {
  const int lane = threadIdx.x & 63;
  unsigned w = x[lane];
  int e = (int)((w >> 7) & 0xffu);
  bool bf = (e >= 100 && e <= 140);
  unsigned long long m = __ballot(bf);
  if (lane == 0) *flag = (__popcll(m) >= 32) ? 1 : 0;
}

// K0b: weights AND x -> bf16 in one launch.
// dst layout: [Wq,Wk,Wv,Wc,Wa,Wco | dwk 1536 | dwb 512 | dwkT 3x512]; xb separate.
constexpr int kW8 = kWAll / 8;        // 196608
constexpr int kX8 = kBN * kC / 8;     // 524288
__global__ __launch_bounds__(256) void convert_all(
    const void* Wq, const void* Wk, const void* Wv, const void* Wc,
    const void* Wa, const void* Wco, const void* dwk, const void* dwb,
    const void* x, const int* __restrict__ flag, short* __restrict__ dst,
    short* __restrict__ xb) {
  const int gtid = blockIdx.x * 256 + threadIdx.x;
  const bool bf = (*flag != 0);
  if (gtid < kW8) {
    const int e = gtid * 8;
    const int t = e >> 18, off = e & (kWElems - 1);
    const void* src = (t == 0) ? Wq : (t == 1) ? Wk : (t == 2) ? Wv
                    : (t == 3) ? Wc : (t == 4) ? Wa : Wco;
    bf16x8 v = bf ? ld8((const short*)src + off) : ld8((const float*)src + off);
    *(bf16x8*)(dst + e) = v;
  } else if (gtid < kW8 + kWExtra) {
    const int eoff = gtid - kW8;
    if (eoff < 1536) {
      dst[kWAll + eoff] = bf ? ((const short*)dwk)[eoff]
                             : f2bf(((const float*)dwk)[eoff]);
    } else if (eoff < 2048) {
      const int i = eoff - 1536;
      dst[kWAll + 1536 + i] = bf ? ((const short*)dwb)[i]
                                 : f2bf(((const float*)dwb)[i]);
    } else {
      const int t2 = eoff - 2048;
      const int tap = t2 >> 9, c = t2 & 511;
      dst[kWAll + 2048 + t2] = bf ? ((const short*)dwk)[c * 3 + tap]
                                  : f2bf(((const float*)dwk)[c * 3 + tap]);
    }
  } else if (gtid < kW8 + kWExtra + kX8) {
    const int e = (gtid - kW8 - kWExtra) * 8;
    bf16x8 v = bf ? ld8((const short*)x + e) : ld8((const float*)x + e);
    *(bf16x8*)(xb + e) = v;
  }
}

// ---------------------------------------------------------------------------
// K1: fused input projection GEMM [8192x512] x [2048x512]^T.
// BK=64, XOR-source-swizzled staging. LDS-bounce epilogue: acc -> swizzled
// 32KB LDS tile (transposed for the vT output), then coalesced b128 stores.
// ---------------------------------------------------------------------------
__global__ __launch_bounds__(256, 3) void proj_gemm(
    const short* __restrict__ xb, const short* __restrict__ wb,
    short* __restrict__ q, short* __restrict__ k, short* __restrict__ vT,
    short* __restrict__ ci) {
  __shared__ __align__(16) short Sh[16384];     // 32 KB: As | Bs, reused by epilogue
  short* As = Sh;                               // 128*64
  short* Bs = Sh + 8192;                        // 128*64
  const int t = threadIdx.x;
  const int wave = t >> 6, lane = t & 63;
  const int row = lane & 15, quad = lane >> 4;
  const int bn = blockIdx.x & 15;
  const int bm = blockIdx.x >> 4;
  const int m0 = bm * 128, n0 = bn * 128;
  const int wm = wave & 1, wn = wave >> 1;
  const int lrow = lane >> 3, lch = lane & 7;   // staging: 8 rows x 8 chunks

  f32x4 acc[4][4];
#pragma unroll
  for (int mi = 0; mi < 4; ++mi)
#pragma unroll
    for (int ni = 0; ni < 4; ++ni)
#pragma unroll
      for (int r = 0; r < 4; ++r) acc[mi][ni][r] = 0.0f;

  for (int k0 = 0; k0 < kC; k0 += 64) {
#pragma unroll
    for (int p = 0; p < 4; ++p) {
      const int m = wave * 32 + p * 8 + lrow;     // tile row this lane stages
      const int kch = lch ^ (m & 7);              // swizzled source chunk
      gload_lds16(xb + (size_t)(m0 + m) * kC + k0 + kch * 8,
                  &As[(wave * 32 + p * 8) * 64]);
      gload_lds16(wb + (size_t)(n0 + m) * kC + k0 + kch * 8,
                  &Bs[(wave * 32 + p * 8) * 64]);
    }
    __syncthreads();

#pragma unroll
    for (int kk2 = 0; kk2 < 2; ++kk2) {
      bf16x8 af[4], bfr[4];
#pragma unroll
      for (int mi = 0; mi < 4; ++mi) {
        const int m = wm * 64 + mi * 16 + row;
        const int ch = (kk2 * 4 + quad) ^ (m & 7);
        af[mi] = *(const bf16x8*)(&As[m * 64 + ch * 8]);
      }
#pragma unroll
      for (int ni = 0; ni < 4; ++ni) {
        const int n = wn * 64 + ni * 16 + row;
        const int ch = (kk2 * 4 + quad) ^ (n & 7);
        bfr[ni] = *(const bf16x8*)(&Bs[n * 64 + ch * 8]);
      }
#pragma unroll
      for (int mi = 0; mi < 4; ++mi)
#pragma unroll
        for (int ni = 0; ni < 4; ++ni)
          acc[mi][ni] = __builtin_amdgcn_mfma_f32_16x16x32_bf16(
              af[mi], bfr[ni], acc[mi][ni], 0, 0, 0);
    }
    __syncthreads();
  }

  // ---- epilogue: LDS bounce -> coalesced stores ----
  // Block's 128-channel span lies in exactly one mat (128 | 512).
  const int mat = n0 >> 9;
  const float scale = (mat == 0) ? kQScale : 1.0f;
  if (mat != 2) {
    // Ep[token m][chan n], 16B-chunk XOR swizzle (slot = (n>>3)^(m&15))
#pragma unroll
    for (int mi = 0; mi < 4; ++mi)
#pragma unroll
      for (int ni = 0; ni < 4; ++ni)
#pragma unroll
        for (int r = 0; r < 4; ++r) {
          const int m = wm * 64 + mi * 16 + quad * 4 + r;
          const int n = wn * 64 + ni * 16 + row;
          Sh[m * 128 + (((n >> 3) ^ (m & 15)) * 8) + (n & 7)] =
              f2bf(acc[mi][ni][r] * scale);
        }
  } else {
    // vT output: store transposed Ep[chan n][token m]
#pragma unroll
    for (int mi = 0; mi < 4; ++mi)
#pragma unroll
      for (int ni = 0; ni < 4; ++ni)
#pragma unroll
        for (int r = 0; r < 4; ++r) {
          const int m = wm * 64 + mi * 16 + quad * 4 + r;
          const int n = wn * 64 + ni * 16 + row;
          Sh[n * 128 + (((m >> 3) ^ (n & 15)) * 8) + (m & 7)] =
              f2bf(acc[mi][ni][r]);
        }
  }
  __syncthreads();
  const int b_ = m0 >> 12;                    // batch index (tokens 4096/batch)
  const int rsub = lane >> 4, chk = lane & 15;
#pragma unroll
  for (int i = 0; i < 8; ++i) {
    const int rr = i * 16 + wave * 4 + rsub;  // Ep row (token, or chan for vT)
    bf16x8 v = *(const bf16x8*)(&Sh[rr * 128 + ((chk ^ (rr & 15)) * 8)]);
    if (mat == 2) {
      const int cg = (n0 + rr) & 511;
      const int h = cg >> 6, d = cg & 63;
      const int nb = (m0 & (kN - 1)) + chk * 8;
      *(bf16x8*)(vT + ((size_t)((b_ * kNH + h) * kHD + d)) * kN + nb) = v;
    } else {
      const int n_ = (m0 & (kN - 1)) + rr;
      const int cg = (n0 + chk * 8) & 511;
      if (mat == 3) {
        *(bf16x8*)(ci + ((size_t)(b_ * kN + n_)) * kC + cg) = v;
      } else {
        const int h = cg >> 6, d = cg & 63;
        short* dst = (mat == 0) ? q : k;
        *(bf16x8*)(dst + ((size_t)((b_ * kNH + h) * kN + n_)) * kHD + d) = v;
      }
    }
  }
}

// K2: depthwise conv, vectorized bf16x8 (uses dwkT + dwb from wb).
__global__ __launch_bounds__(256) void dwconv(
    const short* __restrict__ ci, const short* __restrict__ wb,
    short* __restrict__ cb) {
  const int e0 = (blockIdx.x * 256 + threadIdx.x) * 8;
  const int c0 = e0 & (kC - 1);
  const int bn = e0 >> 9;
  const int n_ = bn & (kN - 1);
  bf16x8 xc = ld8(ci + e0);
  bf16x8 xm, xp;
  if (n_ > 0) xm = ld8(ci + e0 - kC);
  else
#pragma unroll
    for (int i = 0; i < 8; ++i) xm[i] = 0;
  if (n_ < kN - 1) xp = ld8(ci + e0 + kC);
  else
#pragma unroll
    for (int i = 0; i < 8; ++i) xp[i] = 0;
  bf16x8 w0 = ld8(wb + kWAll + 2048 + c0);
  bf16x8 w1 = ld8(wb + kWAll + 2048 + 512 + c0);
  bf16x8 w2 = ld8(wb + kWAll + 2048 + 1024 + c0);
  bf16x8 bi = ld8(wb + kWAll + 1536 + c0);
  bf16x8 o;
#pragma unroll
  for (int i = 0; i < 8; ++i) {
    float a = bf2f(bi[i]) + bf2f(xm[i]) * bf2f(w0[i]) +
              bf2f(xc[i]) * bf2f(w1[i]) + bf2f(xp[i]) * bf2f(w2[i]);
    o[i] = f2bf(a);
  }
  *(bf16x8*)(cb + e0) = o;
}

// ---------------------------------------------------------------------------
// K3: flash attention v9 — 64 q-rows per wave (halved LDS-read volume).
//  - 8 waves = 4 q-groups x 2 key-streams; per-wave q-rows 32 -> 64 (4 groups
//    of 16). Each K/V LDS tile read (8+8 b128/wave/kt) now serves 2x the
//    FLOPs: chip LDS reads 2.15 GB -> 1.07 GB (~41 -> ~21 us occupancy).
//    Per-wave ILP doubles (32 indep QK MFMAs, 64 exp2) -> tolerates the
//    2 waves/SIMD occupancy this costs (VGPR ~200).
//  - Block q-tile 256, grid 256 = 1 block/CU. LDS unified 69632 B buffer:
//    K (2x2x64x64) | V (2x2x64x72); epilogue overlay Of 64KB + Lf 4KB.
//  - K via gload_lds (XOR-source swizzle); V manual permuted staging.
//  - ks=1 partials combined into ks=0 via LDS overlay.
// ---------------------------------------------------------------------------
__global__ __launch_bounds__(512, 2) void attn_flash(
    const short* __restrict__ q, const short* __restrict__ k,
    const short* __restrict__ vT, short* __restrict__ attn) {
  __shared__ __align__(16) short SMEM[34816];          // 69632 B total
  short* Kb = SMEM;                                    // [2][2][64*64] 32 KB
  short* Vb = SMEM + 16384;                            // [2][2][64*72] 36 KB
  const int t = threadIdx.x;
  const int wave = t >> 6;           // 0..7
  const int lane = t & 63;
  const int row = lane & 15;
  const int quad = lane >> 4;
  const int qg = wave & 3;           // q-group (64 rows each)
  const int ks = wave >> 2;          // key-stream (0: keys 0..2047, 1: rest)

  const int slot = blockIdx.x & 7;
  const int inner = blockIdx.x >> 3;          // 0..31
  const int bh = slot * 2 + (inner & 1);
  const int q0 = (inner >> 1) * 256 + qg * 64;

  const short* qbase = q + (size_t)(bh * kN + q0) * kHD;
  const short* kbase = k + (size_t)bh * kN * kHD;
  const short* vbase = vT + (size_t)bh * kHD * kN;

  bf16x8 qb[4][2];
#pragma unroll
  for (int g = 0; g < 4; ++g) {
    qb[g][0] = *(const bf16x8*)(qbase + (g * 16 + row) * kHD + quad * 8);
    qb[g][1] = *(const bf16x8*)(qbase + (g * 16 + row) * kHD + 32 + quad * 8);
  }

  const f32x4 z4 = {0.0f, 0.0f, 0.0f, 0.0f};   // persistent zero C-block

  f32x4 o[4][4];   // O^T partial accumulators (this wave's key half)
#pragma unroll
  for (int g = 0; g < 4; ++g)
#pragma unroll
    for (int j = 0; j < 4; ++j)
#pragma unroll
      for (int r = 0; r < 4; ++r) o[g][j][r] = 0.0f;
  float l_[4] = {0.0f, 0.0f, 0.0f, 0.0f};

  // K staging (gload_lds): XOR-source swizzle, read side XORs back.
  const int ksrow = lane >> 3;
  const int kschunk = (lane & 7) ^ ksrow;
  auto stage_k = [&](int buf, int kt) {
#pragma unroll
    for (int s2 = 0; s2 < 2; ++s2)
      gload_lds16(
          kbase + (size_t)(s2 * 2048 + kt * 64 + wave * 8 + ksrow) * 64 +
              kschunk * 8,
          &Kb[(buf * 2 + s2) * 4096 + wave * 512]);
  };

  // V staging: threads 0-255 stage stream-0 tile, 256-511 stream-1 tile.
  const int sv = t >> 8;
  const int ii = t & 255;
  const int i0 = ii, i1 = ii + 256;
  const int sr0 = i0 >> 3, sc0 = i0 & 7;
  const int sr1 = i1 >> 3, sc1 = i1 & 7;
  const int vb0 = (sc0 >> 2) * 32 + (sc0 & 1) * 16 + (sc0 & 2) * 2;
  const int vb1 = (sc1 >> 2) * 32 + (sc1 & 1) * 16 + (sc1 & 2) * 2;

  auto stage_v = [&](int buf, bf16x8 v0, bf16x8 v1) {
    short* base = &Vb[(buf * 2 + sv) * 4608];
    *(short4*)(&base[sr0 * 72 + vb0]) = make_short4(v0[0], v0[1], v0[2], v0[3]);
    *(short4*)(&base[sr0 * 72 + vb0 + 8]) = make_short4(v0[4], v0[5], v0[6], v0[7]);
    *(short4*)(&base[sr1 * 72 + vb1]) = make_short4(v1[0], v1[1], v1[2], v1[3]);
    *(short4*)(&base[sr1 * 72 + vb1 + 8]) = make_short4(v1[4], v1[5], v1[6], v1[7]);
  };

  // fragment-read chunk offsets (constant per lane)
  const int c0s = ((quad) ^ (row & 7)) * 8;
  const int c1s = ((quad + 4) ^ (row & 7)) * 8;

  // per-tile compute: QK -> softmax -> PV (4 q-groups)
  auto tile_step = [&](const short* kt_base, const short* vt_base) {
    f32x4 s[4][4];
    __builtin_amdgcn_s_setprio(1);
#pragma unroll
    for (int jk = 0; jk < 4; ++jk) {
      const short* kr = kt_base + (jk * 16 + row) * 64;
      bf16x8 a0 = *(const bf16x8*)(kr + c0s);
      bf16x8 a1 = *(const bf16x8*)(kr + c1s);
#pragma unroll
      for (int g = 0; g < 4; ++g) {
        s[g][jk] = __builtin_amdgcn_mfma_f32_16x16x32_bf16(a0, qb[g][0], z4, 0, 0, 0);
        s[g][jk] = __builtin_amdgcn_mfma_f32_16x16x32_bf16(a1, qb[g][1], s[g][jk], 0, 0, 0);
      }
    }
    __builtin_amdgcn_s_setprio(0);

    bf16x8 pb[4][2];
#pragma unroll
    for (int g = 0; g < 4; ++g) {
      float tj[4];
#pragma unroll
      for (int jk = 0; jk < 4; ++jk) {
#pragma unroll
        for (int r = 0; r < 4; ++r) s[g][jk][r] = exp2_(s[g][jk][r]);
        tj[jk] = (s[g][jk][0] + s[g][jk][1]) + (s[g][jk][2] + s[g][jk][3]);
      }
      l_[g] += (tj[0] + tj[1]) + (tj[2] + tj[3]);
#pragma unroll
      for (int c = 0; c < 2; ++c) {
        union { unsigned u[4]; bf16x8 v; } pu;
        pu.u[0] = pk2bf(s[g][2 * c][0], s[g][2 * c][1]);
        pu.u[1] = pk2bf(s[g][2 * c][2], s[g][2 * c][3]);
        pu.u[2] = pk2bf(s[g][2 * c + 1][0], s[g][2 * c + 1][1]);
        pu.u[3] = pk2bf(s[g][2 * c + 1][2], s[g][2 * c + 1][3]);
        pb[g][c] = pu.v;
      }
    }

    __builtin_amdgcn_s_setprio(1);
#pragma unroll
    for (int jd = 0; jd < 4; ++jd) {
      const short* vb = vt_base + (jd * 16 + row) * 72 + quad * 8;
#pragma unroll
      for (int c = 0; c < 2; ++c) {
        bf16x8 av = *(const bf16x8*)(vb + c * 32);
#pragma unroll
        for (int g = 0; g < 4; ++g)
          o[g][jd] = __builtin_amdgcn_mfma_f32_16x16x32_bf16(
              av, pb[g][c], o[g][jd], 0, 0, 0);
      }
    }
    __builtin_amdgcn_s_setprio(0);
  };

  { // prologue: tile 0 of both streams -> buffer 0
    stage_k(0, 0);
    bf16x8 a = *(const bf16x8*)(vbase + (size_t)sr0 * kN + sv * 2048 + sc0 * 8);
    bf16x8 b = *(const bf16x8*)(vbase + (size_t)sr1 * kN + sv * 2048 + sc1 * 8);
    stage_v(0, a, b);
  }
  __syncthreads();

  for (int kt = 0; kt < 32; ++kt) {
    const int cur = kt & 1;
    const bool more = (kt < 31);
    bf16x8 vn0, vn1;
    if (more) {
      stage_k(1 - cur, kt + 1);
      const int off = sv * 2048 + (kt + 1) * 64;
      vn0 = *(const bf16x8*)(vbase + (size_t)sr0 * kN + off + sc0 * 8);
      vn1 = *(const bf16x8*)(vbase + (size_t)sr1 * kN + off + sc1 * 8);
    }

    tile_step(&Kb[(cur * 2 + ks) * 4096], &Vb[(cur * 2 + ks) * 4608]);

    if (more) stage_v(1 - cur, vn0, vn1);
    __syncthreads();
  }

  // ---- combine key-halves via LDS overlay (barrier-protected), finalize ----
  float* Of = (float*)SMEM;            // 64 slots x 256 floats = 64 KB
  float* Lf = (float*)SMEM + 16384;    // 4 slots x 256 floats = 4 KB (fits 69632 B)
  if (ks == 1) {
#pragma unroll
    for (int g = 0; g < 4; ++g) {
#pragma unroll
      for (int jd = 0; jd < 4; ++jd)
#pragma unroll
        for (int r = 0; r < 4; ++r)
          Of[(g * 16 + jd * 4 + r) * 256 + qg * 64 + lane] = o[g][jd][r];
      Lf[g * 256 + qg * 64 + lane] = l_[g];
    }
  }
  __syncthreads();
  if (ks == 0) {
#pragma unroll
    for (int g = 0; g < 4; ++g) {
#pragma unroll
      for (int jd = 0; jd < 4; ++jd)
#pragma unroll
        for (int r = 0; r < 4; ++r)
          o[g][jd][r] += Of[(g * 16 + jd * 4 + r) * 256 + qg * 64 + lane];
      l_[g] += Lf[g * 256 + qg * 64 + lane];
    }
    const int b_ = bh >> 3, h = bh & 7;
#pragma unroll
    for (int g = 0; g < 4; ++g) {
      float lt = l_[g];
      lt += __shfl_xor(lt, 16);
      lt += __shfl_xor(lt, 32);
      const float linv = 1.0f / lt;
      const int n_ = q0 + g * 16 + row;
      short* ob = attn + (size_t)(b_ * kN + n_) * kC + h * kHD + quad * 4;
#pragma unroll
      for (int jd = 0; jd < 4; ++jd) {
        short4 st = make_short4(f2bf(o[g][jd][0] * linv), f2bf(o[g][jd][1] * linv),
                                f2bf(o[g][jd][2] * linv), f2bf(o[g][jd][3] * linv));
        *(short4*)(ob + jd * 16) = st;
      }
    }
  }
}

// ---------------------------------------------------------------------------
// K4: out = [attn|cb] @ [Wa|Wo]^T, GEMM M=8192 N=512 K=1024 (K-concat),
// BK=64, XOR-source-swizzled staging. LDS-bounce epilogue (f32 and bf16).
// ---------------------------------------------------------------------------
template <typename TO>
__device__ __forceinline__ void out_body(
    const short* __restrict__ attn, const short* __restrict__ cb,
    const short* __restrict__ wb, TO* __restrict__ out) {
  __shared__ __align__(16) short Sh[16384];     // 32 KB: As | Bs | epilogue
  short* As = Sh;                               // 128*64
  short* Bs = Sh + 8192;                        // 64*64
  const int t = threadIdx.x;
  const int wave = t >> 6, lane = t & 63;
  const int row = lane & 15, quad = lane >> 4;
  const int bn = blockIdx.x & 7;
  const int bm = blockIdx.x >> 3;
  const int m0 = bm * 128, n0 = bn * 64;
  const int wm = wave & 1, wn = wave >> 1;
  const int lrow = lane >> 3, lch = lane & 7;

  f32x4 acc[4][2];
#pragma unroll
  for (int mi = 0; mi < 4; ++mi)
#pragma unroll
    for (int ni = 0; ni < 2; ++ni)
#pragma unroll
      for (int r = 0; r < 4; ++r) acc[mi][ni][r] = 0.0f;

  const short* Wa = wb + 4 * kWElems;
  const short* Wo = wb + 5 * kWElems;

  for (int k0 = 0; k0 < 1024; k0 += 64) {
    const short* Asrc = (k0 < 512) ? attn : cb;
    const short* Bsrc = (k0 < 512) ? Wa : Wo;
    const int ka = k0 & 511;
#pragma unroll
    for (int p = 0; p < 4; ++p) {
      const int m = wave * 32 + p * 8 + lrow;
      const int kch = lch ^ (m & 7);
      gload_lds16(Asrc + (size_t)(m0 + m) * kC + ka + kch * 8,
                  &As[(wave * 32 + p * 8) * 64]);
    }
#pragma unroll
    for (int p = 0; p < 2; ++p) {
      const int n = wave * 16 + p * 8 + lrow;
      const int kch = lch ^ (n & 7);
      gload_lds16(Bsrc + (size_t)(n0 + n) * kC + ka + kch * 8,
                  &Bs[(wave * 16 + p * 8) * 64]);
    }
    __syncthreads();

#pragma unroll
    for (int kk2 = 0; kk2 < 2; ++kk2) {
      bf16x8 af[4], bfr[2];
#pragma unroll
      for (int mi = 0; mi < 4; ++mi) {
        const int m = wm * 64 + mi * 16 + row;
        const int ch = (kk2 * 4 + quad) ^ (m & 7);
        af[mi] = *(const bf16x8*)(&As[m * 64 + ch * 8]);
      }
#pragma unroll
      for (int ni = 0; ni < 2; ++ni) {
        const int n = wn * 32 + ni * 16 + row;
        const int ch = (kk2 * 4 + quad) ^ (n & 7);
        bfr[ni] = *(const bf16x8*)(&Bs[n * 64 + ch * 8]);
      }
#pragma unroll
      for (int mi = 0; mi < 4; ++mi)
#pragma unroll
        for (int ni = 0; ni < 2; ++ni)
          acc[mi][ni] = __builtin_amdgcn_mfma_f32_16x16x32_bf16(
              af[mi], bfr[ni], acc[mi][ni], 0, 0, 0);
    }
    __syncthreads();
  }

  // ---- epilogue: LDS bounce -> coalesced 16B stores ----
  if constexpr (sizeof(TO) == 4) {
    float* Shf = (float*)Sh;   // 128 x 64 f32 = 32 KB (exact)
#pragma unroll
    for (int mi = 0; mi < 4; ++mi)
#pragma unroll
      for (int ni = 0; ni < 2; ++ni)
#pragma unroll
        for (int r = 0; r < 4; ++r) {
          const int m = wm * 64 + mi * 16 + quad * 4 + r;
          const int n = wn * 32 + ni * 16 + row;
          Shf[m * 64 + (((n >> 2) ^ (m & 15)) * 4) + (n & 3)] = acc[mi][ni][r];
        }
    __syncthreads();
    const int rsub = lane >> 4, chk = lane & 15;
#pragma unroll
    for (int i = 0; i < 8; ++i) {
      const int rr = i * 16 + wave * 4 + rsub;
      float4 v = *(const float4*)(&Shf[rr * 64 + ((chk ^ (rr & 15)) * 4)]);
      *(float4*)((float*)out + (size_t)(m0 + rr) * kC + n0 + chk * 4) = v;
    }
  } else {
#pragma unroll
    for (int mi = 0; mi < 4; ++mi)
#pragma unroll
      for (int ni = 0; ni < 2; ++ni)
#pragma unroll
        for (int r = 0; r < 4; ++r) {
          const int m = wm * 64 + mi * 16 + quad * 4 + r;
          const int n = wn * 32 + ni * 16 + row;
          Sh[m * 64 + (((n >> 3) ^ (m & 7)) * 8) + (n & 7)] =
              f2bf(acc[mi][ni][r]);
        }
    __syncthreads();
    const int rsub = lane >> 3, chk = lane & 7;
#pragma unroll
    for (int i = 0; i < 4; ++i) {
      const int rr = i * 32 + wave * 8 + rsub;
      bf16x8 v = *(const bf16x8*)(&Sh[rr * 64 + ((chk ^ (rr & 7)) * 8)]);
      *(bf16x8*)((short*)out + (size_t)(m0 + rr) * kC + n0 + chk * 8) = v;
    }
  }
}

__global__ __launch_bounds__(256, 4) void out_gemm(
    const short* __restrict__ attn, const short* __restrict__ cb,
    const short* __restrict__ wb, const int* __restrict__ flag, void* out) {
  if (*flag)
    out_body<short>(attn, cb, wb, (short*)out);
  else
    out_body<float>(attn, cb, wb, (float*)out);
}

extern "C" void kernel_launch(void* const* d_in, const int* in_sizes, int n_in,
                              void* d_out, int out_size, void* d_ws, size_t ws_size,
                              hipStream_t stream) {
  const void* x   = d_in[0];
  const void* Wq  = d_in[1];
  const void* Wk  = d_in[2];
  const void* Wv  = d_in[3];
  const void* Wa  = d_in[4];
  const void* Wc  = d_in[5];
  const void* dwk = d_in[6];
  const void* dwb = d_in[7];
  const void* Wco = d_in[8];

  short* ws = (short*)d_ws;
  const size_t E = (size_t)kBN * kC;
  int*   flag = (int*)ws;
  short* wb   = ws + 256;
  short* q    = wb + kWAll + kWExtra;
  short* k    = q + E;
  short* vT   = k + E;
  short* ci   = vT + E;
  short* cb   = ci + E;
  short* attn = ci;   // attn overwrites ci (consumed by dwconv first)
  short* xb   = cb;   // consumed by proj_gemm before dwconv writes cb

  detect_dtype<<<1, 64, 0, stream>>>((const unsigned*)x, flag);
  const int cvt_threads = kW8 + kWExtra + kX8;
  convert_all<<<(cvt_threads + 255) / 256, 256, 0, stream>>>(
      Wq, Wk, Wv, Wc, Wa, Wco, dwk, dwb, x, flag, wb, xb);
  proj_gemm<<<1024, 256, 0, stream>>>(xb, wb, q, k, vT, ci);
  dwconv<<<(kBN * kC) / (256 * 8), 256, 0, stream>>>(ci, wb, cb);
  attn_flash<<<256, 512, 0, stream>>>(q, k, vT, attn);
  out_gemm<<<512, 256, 0, stream>>>(attn, cb, wb, flag, d_out);
}